// Round 2
// baseline (1564.133 us; speedup 1.0000x reference)
//
#include <hip/hip_runtime.h>
#include <hip/hip_bf16.h>
#include <stdint.h>

#define DEV static __device__ __forceinline__

// Problem constants
constexpr int kB = 2, kT = 16, kL = 256, kM = 512;
constexpr int kD = 1024, kH = 16, kDH = 64, kHT = 8, kROT = 32;
constexpr int kN = kT * kL;  // 4096 flattened seq for cross-attn
constexpr float kEPS = 1e-5f;
constexpr float kNEG = -1.0e9f;
constexpr float kSCALE = 0.125f;  // 1/sqrt(64)

typedef __attribute__((ext_vector_type(8))) short short8;   // 8 bf16 (guide §3)
typedef __attribute__((ext_vector_type(4))) float floatx4;

DEV float b2f(__hip_bfloat16 v) { return __bfloat162float(v); }
DEV __hip_bfloat16 f2b(float v) { return __float2bfloat16(v); }

// ---------------- mask conversion ----------------
// Masks are prefix masks with element 1 guaranteed true (lens>=2, clens>=M/2),
// so bytes 1..3 of the raw buffer disambiguate bool8 / int32 / bf16 / fp32.
// NOTE: bf16 check MUST precede fp32 check (bf16 1.0 = 80 3F 80 3F has b3==0x3F too).
__global__ void mask_convert(const unsigned char* __restrict__ raw, int n,
                             int* __restrict__ out) {
  int i = blockIdx.x * blockDim.x + threadIdx.x;
  if (i >= n) return;
  unsigned char b1 = raw[1], b3 = raw[3];
  int v;
  if (b1 == 0x3F) {                                    // bf16: 1.0 = 80 3F
    v = ((const unsigned short*)raw)[i] != 0;
  } else if (b3 == 0x3F) {                             // fp32: 1.0f = 00 00 80 3F
    v = ((const float*)raw)[i] != 0.0f;
  } else if (b1 == 1) {                                // bool bytes
    v = raw[i] != 0;
  } else {                                             // int32: 1 = 01 00 00 00
    v = ((const int*)raw)[i] != 0;
  }
  out[i] = v;
}

// ---------------- weight transpose+downcast W[K][N] fp32 -> Wt[N][K] bf16 ----
__global__ __launch_bounds__(256) void transpose_w(
    const float* __restrict__ W, __hip_bfloat16* __restrict__ Wt,
    int Kd, int Nd) {
  __shared__ float tile[32][33];
  int n0 = blockIdx.x * 32, k0 = blockIdx.y * 32;
  int tx = threadIdx.x & 31, ty = threadIdx.x >> 5;  // ty in 0..7
  for (int i = 0; i < 32; i += 8)
    tile[ty + i][tx] = W[(size_t)(k0 + ty + i) * Nd + n0 + tx];
  __syncthreads();
  for (int i = 0; i < 32; i += 8)
    Wt[(size_t)(n0 + ty + i) * Kd + k0 + tx] = f2b(tile[tx][ty + i]);
}

// ---------------- LayerNorm over D=1024 fp32 in, bf16 out; 1 block/row -----
__global__ __launch_bounds__(256) void ln_rows(
    const float* __restrict__ X, const float* __restrict__ g,
    const float* __restrict__ bb, __hip_bfloat16* __restrict__ out) {
  int row = blockIdx.x, tid = threadIdx.x;
  const float* xr = X + (size_t)row * kD;
  float v[4], s = 0.f, s2 = 0.f;
  for (int j = 0; j < 4; j++) {
    float t = xr[tid + j * 256];
    v[j] = t; s += t; s2 += t * t;
  }
  for (int off = 32; off; off >>= 1) {
    s += __shfl_down(s, off);
    s2 += __shfl_down(s2, off);
  }
  __shared__ float rs[4], rs2[4];
  if ((tid & 63) == 0) { rs[tid >> 6] = s; rs2[tid >> 6] = s2; }
  __syncthreads();
  float ts = rs[0] + rs[1] + rs[2] + rs[3];
  float ts2 = rs2[0] + rs2[1] + rs2[2] + rs2[3];
  float mu = ts * (1.f / kD);
  float var = ts2 * (1.f / kD) - mu * mu;
  float rstd = rsqrtf(var + kEPS);
  for (int j = 0; j < 4; j++) {
    int idx = tid + j * 256;
    float o = (v[j] - mu) * rstd * g[idx] + bb[idx];
    out[(size_t)row * kD + idx] = f2b(o);
  }
}

// ---------------- MFMA GEMM: C[M][N] = act(A[M][K] @ Bt[N][K]^T + bias) + res
// 64x64 block tile, BK=32, 4 waves in 2x2, each wave 2x2 frags of 16x16x32.
// Fragment mapping per guide §3 (m89/m91-verified):
//   A: lane holds A[m=lane&15][k=quad*8+j]; B: B[k=quad*8+j][n=lane&15]
//   D: reg r -> row=quad*4+r, col=lane&15
__global__ __launch_bounds__(256) void gemm_bf16(
    const __hip_bfloat16* __restrict__ A,    // [Md][Kd]
    const __hip_bfloat16* __restrict__ Bt,   // [Nd][Kd]
    const float* __restrict__ bias,          // [Nd] fp32 or null
    const float* __restrict__ res,           // [Md][Nd] fp32 or null
    int gelu,
    void* __restrict__ out, int outBf16,
    int Md, int Nd, int Kd) {
  __shared__ __align__(16) __hip_bfloat16 As[64][40];  // pad 8 -> 2-way (free)
  __shared__ __align__(16) __hip_bfloat16 Bs[64][40];
  int m0 = blockIdx.x * 64, n0 = blockIdx.y * 64;
  int tid = threadIdx.x;
  int wave = tid >> 6, lane = tid & 63;
  int l16 = lane & 15, quad = lane >> 4;
  int wm = (wave >> 1) * 32, wn = (wave & 1) * 32;
  floatx4 acc[2][2] = {};
  int ar = tid >> 2, ac = (tid & 3) << 3;
  const __hip_bfloat16* Arow = A + (size_t)(m0 + ar) * Kd + ac;
  const __hip_bfloat16* Brow = Bt + (size_t)(n0 + ar) * Kd + ac;
  for (int k0 = 0; k0 < Kd; k0 += 32) {
    *(uint4*)(&As[ar][ac]) = *(const uint4*)(Arow + k0);
    *(uint4*)(&Bs[ar][ac]) = *(const uint4*)(Brow + k0);
    __syncthreads();
    short8 a0 = *(const short8*)(&As[wm + l16][quad * 8]);
    short8 a1 = *(const short8*)(&As[wm + 16 + l16][quad * 8]);
    short8 b0 = *(const short8*)(&Bs[wn + l16][quad * 8]);
    short8 b1 = *(const short8*)(&Bs[wn + 16 + l16][quad * 8]);
    acc[0][0] = __builtin_amdgcn_mfma_f32_16x16x32_bf16(a0, b0, acc[0][0], 0, 0, 0);
    acc[0][1] = __builtin_amdgcn_mfma_f32_16x16x32_bf16(a0, b1, acc[0][1], 0, 0, 0);
    acc[1][0] = __builtin_amdgcn_mfma_f32_16x16x32_bf16(a1, b0, acc[1][0], 0, 0, 0);
    acc[1][1] = __builtin_amdgcn_mfma_f32_16x16x32_bf16(a1, b1, acc[1][1], 0, 0, 0);
    __syncthreads();
  }
  for (int i = 0; i < 2; i++) {
    for (int j = 0; j < 2; j++) {
      int col = n0 + wn + j * 16 + l16;
      float bv = bias ? bias[col] : 0.f;
      for (int r = 0; r < 4; r++) {
        int row = m0 + wm + i * 16 + quad * 4 + r;
        float v = acc[i][j][r] + bv;
        if (gelu) v = 0.5f * v * (1.f + erff(v * 0.70710678118f));
        size_t o = (size_t)row * Nd + col;
        if (res) v += res[o];
        if (outBf16) ((__hip_bfloat16*)out)[o] = f2b(v);
        else         ((float*)out)[o] = v;
      }
    }
  }
}

// ---------------- cross-attention ----------------
// grid (N/16, B*H); block 256. Q tile 16 rows, full M=512 scores in LDS.
__global__ __launch_bounds__(256) void cross_attn(
    const __hip_bfloat16* __restrict__ Qb,   // [B*N][1024]
    const __hip_bfloat16* __restrict__ KVb,  // [B*M][2048] (k | v)
    const int* __restrict__ cmask,           // [B*M]
    __hip_bfloat16* __restrict__ Ob) {       // [B*N][1024]
  __shared__ float Qs[16][65];
  __shared__ float Ks[64][65];       // reused for V tiles
  __shared__ float Ss[16][kM + 1];   // 513 stride breaks bank aliasing
  int bh = blockIdx.y;
  int b = bh >> 4, h = bh & 15;
  int q0 = blockIdx.x * 16;
  int tid = threadIdx.x;

  {  // load + scale Q tile
    int q = tid >> 4, c0 = (tid & 15) * 4;
    const __hip_bfloat16* src = Qb + (size_t)(b * kN + q0 + q) * 1024 + h * 64 + c0;
    for (int j = 0; j < 4; j++) Qs[q][c0 + j] = b2f(src[j]) * kSCALE;
  }
  // scores
  int sq = tid >> 4, sm = tid & 15;
  for (int mt = 0; mt < kM; mt += 64) {
    __syncthreads();
    {  // stage K tile (fp32 in LDS)
      int mm = tid >> 2, c0 = (tid & 3) * 16;
      const __hip_bfloat16* src = KVb + (size_t)(b * kM + mt + mm) * 2048 + h * 64 + c0;
      for (int j = 0; j < 16; j++) Ks[mm][c0 + j] = b2f(src[j]);
    }
    __syncthreads();
    int kr = sm * 4;
    float s0 = 0, s1 = 0, s2 = 0, s3 = 0;
    for (int d = 0; d < 64; d++) {
      float qv = Qs[sq][d];
      s0 += qv * Ks[kr + 0][d];
      s1 += qv * Ks[kr + 1][d];
      s2 += qv * Ks[kr + 2][d];
      s3 += qv * Ks[kr + 3][d];
    }
    Ss[sq][mt + kr + 0] = s0;
    Ss[sq][mt + kr + 1] = s1;
    Ss[sq][mt + kr + 2] = s2;
    Ss[sq][mt + kr + 3] = s3;
  }
  __syncthreads();
  // softmax: wave w handles rows 4w..4w+3, 8 elems per lane
  int wave = tid >> 6, lane = tid & 63;
  for (int q = wave * 4; q < wave * 4 + 4; q++) {
    float vals[8];
    float mx = -1e30f;
    for (int k = 0; k < 8; k++) {
      int m = lane + k * 64;
      float v = cmask[b * kM + m] ? Ss[q][m] : kNEG;
      vals[k] = v;
      mx = fmaxf(mx, v);
    }
    for (int o = 1; o < 64; o <<= 1) mx = fmaxf(mx, __shfl_xor(mx, o));
    float sum = 0.f;
    for (int k = 0; k < 8; k++) { float p = __expf(vals[k] - mx); vals[k] = p; sum += p; }
    for (int o = 1; o < 64; o <<= 1) sum += __shfl_xor(sum, o);
    float inv = 1.f / sum;
    for (int k = 0; k < 8; k++) Ss[q][lane + k * 64] = vals[k] * inv;
  }
  // PV
  int oq = tid >> 4, dg = tid & 15;
  float o0 = 0, o1 = 0, o2 = 0, o3 = 0;
  for (int mt = 0; mt < kM; mt += 64) {
    __syncthreads();
    {  // stage V tile
      int mm = tid >> 2, c0 = (tid & 3) * 16;
      const __hip_bfloat16* src =
          KVb + (size_t)(b * kM + mt + mm) * 2048 + 1024 + h * 64 + c0;
      for (int j = 0; j < 16; j++) Ks[mm][c0 + j] = b2f(src[j]);
    }
    __syncthreads();
    for (int mm = 0; mm < 64; mm++) {
      float p = Ss[oq][mt + mm];
      o0 += p * Ks[mm][dg];
      o1 += p * Ks[mm][dg + 16];
      o2 += p * Ks[mm][dg + 32];
      o3 += p * Ks[mm][dg + 48];
    }
  }
  __hip_bfloat16* dst = Ob + (size_t)(b * kN + q0 + oq) * 1024 + h * 64;
  dst[dg] = f2b(o0);
  dst[dg + 16] = f2b(o1);
  dst[dg + 32] = f2b(o2);
  dst[dg + 48] = f2b(o3);
}

// ---------------- temporal attention (with RoPE) ----------------
// grid B*L*HT, block 64 (one wave). T=16 q/k/v rows of DH=64 in LDS.
__global__ __launch_bounds__(64) void temporal_attn(
    const __hip_bfloat16* __restrict__ QKVb,  // [B*T*L][1536] (q|k|v)
    const float* __restrict__ rope,           // [T][32] fp32
    const int* __restrict__ amask,            // [B*T]
    __hip_bfloat16* __restrict__ Otb) {       // [B*T*L][512]
  __shared__ float qs[16][65], ks[16][65], vs[16][65];
  __shared__ float Ps[16][17];
  int idx = blockIdx.x;
  int h = idx & 7, l = (idx >> 3) & 255, b = idx >> 11;
  int lane = threadIdx.x;

  {  // load q,k,v (q pre-scaled; RoPE is linear, so scaling commutes)
    int tr = lane >> 2, c0 = (lane & 3) * 16;
    size_t rowbase = ((size_t)(b * kT + tr) * kL + l) * 1536 + h * 64;
    for (int j = 0; j < 16; j++) {
      qs[tr][c0 + j] = b2f(QKVb[rowbase + c0 + j]) * kSCALE;
      ks[tr][c0 + j] = b2f(QKVb[rowbase + 512 + c0 + j]);
      vs[tr][c0 + j] = b2f(QKVb[rowbase + 1024 + c0 + j]);
    }
  }
  __syncthreads();
  {  // RoPE on first 32 dims: out[d] = x[d]*cos + (d<16 ? -x[d+16] : x[d-16])*sin
    int rt = lane >> 2, rd0 = (lane & 3) * 8;
    float nq[8], nk[8];
    for (int j = 0; j < 8; j++) {
      int d = rd0 + j;
      float ang = rope[rt * kROT + d];
      float cv = cosf(ang), sv = sinf(ang);
      float oq = (d < 16) ? -qs[rt][d + 16] : qs[rt][d - 16];
      float ok = (d < 16) ? -ks[rt][d + 16] : ks[rt][d - 16];
      nq[j] = qs[rt][d] * cv + oq * sv;
      nk[j] = ks[rt][d] * cv + ok * sv;
    }
    __syncthreads();
    for (int j = 0; j < 8; j++) { qs[rt][rd0 + j] = nq[j]; ks[rt][rd0 + j] = nk[j]; }
  }
  __syncthreads();
  {  // scores 16x16
    int tq = lane >> 2, tk0 = (lane & 3) * 4;
    float s[4] = {0, 0, 0, 0};
    for (int d = 0; d < 64; d++) {
      float qv = qs[tq][d];
      s[0] += qv * ks[tk0 + 0][d];
      s[1] += qv * ks[tk0 + 1][d];
      s[2] += qv * ks[tk0 + 2][d];
      s[3] += qv * ks[tk0 + 3][d];
    }
    for (int jj = 0; jj < 4; jj++)
      Ps[tq][tk0 + jj] = amask[b * kT + tk0 + jj] ? s[jj] : kNEG;
  }
  __syncthreads();
  if (lane < 16) {  // softmax, one row per lane
    float mx = -1e30f;
    for (int k = 0; k < 16; k++) mx = fmaxf(mx, Ps[lane][k]);
    float sum = 0.f;
    for (int k = 0; k < 16; k++) { float p = __expf(Ps[lane][k] - mx); Ps[lane][k] = p; sum += p; }
    float inv = 1.f / sum;
    for (int k = 0; k < 16; k++) Ps[lane][k] *= inv;
  }
  __syncthreads();
  // PV: lane = output dim d
  for (int tq = 0; tq < 16; tq++) {
    float acc = 0.f;
    for (int tk = 0; tk < 16; tk++) acc += Ps[tq][tk] * vs[tk][lane];
    float qm = amask[b * kT + tq] ? 1.f : 0.f;
    Otb[((size_t)(b * kT + tq) * kL + l) * 512 + h * 64 + lane] = f2b(acc * qm);
  }
}

// ---------------- launcher ----------------
extern "C" void kernel_launch(void* const* d_in, const int* in_sizes, int n_in,
                              void* d_out, int out_size, void* d_ws, size_t ws_size,
                              hipStream_t stream) {
  // Reference dtypes are all float32 -> fp32 pointers (round-1 fix: NaN
  // signature proved inputs are fp32, not bf16).
  const float* x       = (const float*)d_in[0];
  const float* ctx     = (const float*)d_in[1];
  const float* rope    = (const float*)d_in[2];
  const float* ca_ng   = (const float*)d_in[3];
  const float* ca_nb   = (const float*)d_in[4];
  const float* ca_cng  = (const float*)d_in[5];
  const float* ca_cnb  = (const float*)d_in[6];
  const float* ca_wq   = (const float*)d_in[7];
  const float* ca_wkv  = (const float*)d_in[8];
  const float* ca_wo   = (const float*)d_in[9];
  const float* ta_ng   = (const float*)d_in[10];
  const float* ta_nb   = (const float*)d_in[11];
  const float* ta_wqkv = (const float*)d_in[12];
  const float* ta_bqkv = (const float*)d_in[13];
  const float* ta_wo   = (const float*)d_in[14];
  const float* ff_ng   = (const float*)d_in[15];
  const float* ff_nb   = (const float*)d_in[16];
  const float* ff_w1   = (const float*)d_in[17];
  const float* ff_w2   = (const float*)d_in[18];
  const unsigned char* cmraw = (const unsigned char*)d_in[19];
  const unsigned char* amraw = (const unsigned char*)d_in[20];

  char* wsc = (char*)d_ws;
  size_t off = 0;
  auto take = [&](size_t bytes) {
    char* p = wsc + off;
    off = (off + bytes + 255) & ~(size_t)255;
    return p;
  };
  // transposed bf16 weights Wt[N][K]
  __hip_bfloat16* wqT   = (__hip_bfloat16*)take((size_t)1024 * 1024 * 2);
  __hip_bfloat16* wkvT  = (__hip_bfloat16*)take((size_t)2048 * 1024 * 2);
  __hip_bfloat16* woT   = (__hip_bfloat16*)take((size_t)1024 * 1024 * 2);
  __hip_bfloat16* wqkvT = (__hip_bfloat16*)take((size_t)1536 * 1024 * 2);
  __hip_bfloat16* tawoT = (__hip_bfloat16*)take((size_t)1024 * 512 * 2);
  __hip_bfloat16* ffw1T = (__hip_bfloat16*)take((size_t)4096 * 1024 * 2);
  __hip_bfloat16* ffw2T = (__hip_bfloat16*)take((size_t)1024 * 4096 * 2);
  // activations
  __hip_bfloat16* XN  = (__hip_bfloat16*)take((size_t)8192 * 1024 * 2);  // ln out (reused x3)
  __hip_bfloat16* CN  = (__hip_bfloat16*)take((size_t)1024 * 1024 * 2);
  __hip_bfloat16* Qb  = (__hip_bfloat16*)take((size_t)8192 * 1024 * 2);  // also OT later
  __hip_bfloat16* KVb = (__hip_bfloat16*)take((size_t)1024 * 2048 * 2);
  __hip_bfloat16* Ob  = (__hip_bfloat16*)take((size_t)8192 * 1024 * 2);
  float*          X1  = (float*)take((size_t)8192 * 1024 * 4);           // fp32 trunk
  __hip_bfloat16* Hb  = (__hip_bfloat16*)take((size_t)8192 * 4096 * 2);  // also QKV earlier
  int* cmask = (int*)take((size_t)kB * kM * 4);
  int* amask = (int*)take((size_t)kB * kT * 4);
  if (off > ws_size) return;  // ws too small: leaves zeros -> absmax ~6.15 signature

  __hip_bfloat16* QKVb = Hb;  // [8192][1536], dead before Hb is written
  __hip_bfloat16* OTb  = Qb;  // [8192][512], Q dead after cross_attn

  auto gemm = [&](const __hip_bfloat16* A, const __hip_bfloat16* Bt,
                  const float* bias, const float* res, int gelu, void* out,
                  int outBf16, int Md, int Nd, int Kd) {
    gemm_bf16<<<dim3(Md / 64, Nd / 64), dim3(256), 0, stream>>>(
        A, Bt, bias, res, gelu, out, outBf16, Md, Nd, Kd);
  };

  // masks
  mask_convert<<<dim3((kB * kM + 255) / 256), dim3(256), 0, stream>>>(cmraw, kB * kM, cmask);
  mask_convert<<<dim3(1), dim3(256), 0, stream>>>(amraw, kB * kT, amask);
  // weight transposes (fp32 -> bf16)
  transpose_w<<<dim3(1024 / 32, 1024 / 32), dim3(256), 0, stream>>>(ca_wq, wqT, 1024, 1024);
  transpose_w<<<dim3(2048 / 32, 1024 / 32), dim3(256), 0, stream>>>(ca_wkv, wkvT, 1024, 2048);
  transpose_w<<<dim3(1024 / 32, 1024 / 32), dim3(256), 0, stream>>>(ca_wo, woT, 1024, 1024);
  transpose_w<<<dim3(1536 / 32, 1024 / 32), dim3(256), 0, stream>>>(ta_wqkv, wqkvT, 1024, 1536);
  transpose_w<<<dim3(1024 / 32, 512 / 32), dim3(256), 0, stream>>>(ta_wo, tawoT, 512, 1024);
  transpose_w<<<dim3(4096 / 32, 1024 / 32), dim3(256), 0, stream>>>(ff_w1, ffw1T, 1024, 4096);
  transpose_w<<<dim3(1024 / 32, 4096 / 32), dim3(256), 0, stream>>>(ff_w2, ffw2T, 4096, 1024);

  // cross-attention block
  ln_rows<<<dim3(8192), dim3(256), 0, stream>>>(x, ca_ng, ca_nb, XN);
  ln_rows<<<dim3(1024), dim3(256), 0, stream>>>(ctx, ca_cng, ca_cnb, CN);
  gemm(XN, wqT, nullptr, nullptr, 0, Qb, 1, 8192, 1024, 1024);       // q
  gemm(CN, wkvT, nullptr, nullptr, 0, KVb, 1, 1024, 2048, 1024);     // kv
  cross_attn<<<dim3(kN / 16, kB * kH), dim3(256), 0, stream>>>(Qb, KVb, cmask, Ob);
  gemm(Ob, woT, nullptr, x, 0, X1, 0, 8192, 1024, 1024);             // x1 = x + o@wo

  // temporal attention block
  ln_rows<<<dim3(8192), dim3(256), 0, stream>>>(X1, ta_ng, ta_nb, XN);
  gemm(XN, wqkvT, ta_bqkv, nullptr, 0, QKVb, 1, 8192, 1536, 1024);   // qkv
  temporal_attn<<<dim3(kB * kL * kHT), dim3(64), 0, stream>>>(QKVb, rope, amask, OTb);
  gemm(OTb, tawoT, nullptr, X1, 0, X1, 0, 8192, 1024, 512);          // x2 = x1 + ot@wo

  // feed-forward block
  ln_rows<<<dim3(8192), dim3(256), 0, stream>>>(X1, ff_ng, ff_nb, XN);
  gemm(XN, ffw1T, nullptr, nullptr, 1, Hb, 1, 8192, 4096, 1024);     // h = gelu(.@w1)
  gemm(Hb, ffw2T, nullptr, X1, 0, d_out, 0, 8192, 1024, 4096);       // out = x2 + h@w2
}

// Round 3
// 810.966 us; speedup vs baseline: 1.9287x; 1.9287x over previous
//
#include <hip/hip_runtime.h>
#include <hip/hip_bf16.h>
#include <stdint.h>

#define DEV static __device__ __forceinline__

// Problem constants
constexpr int kB = 2, kT = 16, kL = 256, kM = 512;
constexpr int kD = 1024, kH = 16, kDH = 64, kHT = 8, kROT = 32;
constexpr int kN = kT * kL;  // 4096 flattened seq for cross-attn
constexpr float kEPS = 1e-5f;
constexpr float kNEG = -1.0e9f;
constexpr float kSCALE = 0.125f;  // 1/sqrt(64)

typedef __attribute__((ext_vector_type(8))) short short8;   // 8 bf16 (guide §3)
typedef __attribute__((ext_vector_type(4))) float floatx4;

DEV float b2f(__hip_bfloat16 v) { return __bfloat162float(v); }
DEV __hip_bfloat16 f2b(float v) { return __float2bfloat16(v); }

// ---------------- mask conversion ----------------
__global__ void mask_convert(const unsigned char* __restrict__ raw, int n,
                             int* __restrict__ out) {
  int i = blockIdx.x * blockDim.x + threadIdx.x;
  if (i >= n) return;
  unsigned char b1 = raw[1], b3 = raw[3];
  int v;
  if (b1 == 0x3F) {                                    // bf16: 1.0 = 80 3F
    v = ((const unsigned short*)raw)[i] != 0;
  } else if (b3 == 0x3F) {                             // fp32: 1.0f = 00 00 80 3F
    v = ((const float*)raw)[i] != 0.0f;
  } else if (b1 == 1) {                                // bool bytes
    v = raw[i] != 0;
  } else {                                             // int32
    v = ((const int*)raw)[i] != 0;
  }
  out[i] = v;
}

// ---------------- weight transpose+downcast W[K][N] fp32 -> Wt[N][K] bf16 ----
__global__ __launch_bounds__(256) void transpose_w(
    const float* __restrict__ W, __hip_bfloat16* __restrict__ Wt,
    int Kd, int Nd) {
  __shared__ float tile[32][33];
  int n0 = blockIdx.x * 32, k0 = blockIdx.y * 32;
  int tx = threadIdx.x & 31, ty = threadIdx.x >> 5;
  for (int i = 0; i < 32; i += 8)
    tile[ty + i][tx] = W[(size_t)(k0 + ty + i) * Nd + n0 + tx];
  __syncthreads();
  for (int i = 0; i < 32; i += 8)
    Wt[(size_t)(n0 + ty + i) * Kd + k0 + tx] = f2b(tile[tx][ty + i]);
}

// ---------------- LayerNorm over D=1024 fp32 in, bf16 out; 1 block/row -----
__global__ __launch_bounds__(256) void ln_rows(
    const float* __restrict__ X, const float* __restrict__ g,
    const float* __restrict__ bb, __hip_bfloat16* __restrict__ out) {
  int row = blockIdx.x, tid = threadIdx.x;
  const float* xr = X + (size_t)row * kD;
  float v[4], s = 0.f, s2 = 0.f;
  for (int j = 0; j < 4; j++) {
    float t = xr[tid + j * 256];
    v[j] = t; s += t; s2 += t * t;
  }
  for (int off = 32; off; off >>= 1) {
    s += __shfl_down(s, off);
    s2 += __shfl_down(s2, off);
  }
  __shared__ float rs[4], rs2[4];
  if ((tid & 63) == 0) { rs[tid >> 6] = s; rs2[tid >> 6] = s2; }
  __syncthreads();
  float ts = rs[0] + rs[1] + rs[2] + rs[3];
  float ts2 = rs2[0] + rs2[1] + rs2[2] + rs2[3];
  float mu = ts * (1.f / kD);
  float var = ts2 * (1.f / kD) - mu * mu;
  float rstd = rsqrtf(var + kEPS);
  for (int j = 0; j < 4; j++) {
    int idx = tid + j * 256;
    float o = (v[j] - mu) * rstd * g[idx] + bb[idx];
    out[(size_t)row * kD + idx] = f2b(o);
  }
}

// ---------------- MFMA GEMM (unchanged this round) ----------------
__global__ __launch_bounds__(256) void gemm_bf16(
    const __hip_bfloat16* __restrict__ A,    // [Md][Kd]
    const __hip_bfloat16* __restrict__ Bt,   // [Nd][Kd]
    const float* __restrict__ bias,          // [Nd] or null
    const float* __restrict__ res,           // [Md][Nd] fp32 or null
    int gelu,
    void* __restrict__ out, int outBf16,
    int Md, int Nd, int Kd) {
  __shared__ __align__(16) __hip_bfloat16 As[64][40];
  __shared__ __align__(16) __hip_bfloat16 Bs[64][40];
  int m0 = blockIdx.x * 64, n0 = blockIdx.y * 64;
  int tid = threadIdx.x;
  int wave = tid >> 6, lane = tid & 63;
  int l16 = lane & 15, quad = lane >> 4;
  int wm = (wave >> 1) * 32, wn = (wave & 1) * 32;
  floatx4 acc[2][2] = {};
  int ar = tid >> 2, ac = (tid & 3) << 3;
  const __hip_bfloat16* Arow = A + (size_t)(m0 + ar) * Kd + ac;
  const __hip_bfloat16* Brow = Bt + (size_t)(n0 + ar) * Kd + ac;
  for (int k0 = 0; k0 < Kd; k0 += 32) {
    *(uint4*)(&As[ar][ac]) = *(const uint4*)(Arow + k0);
    *(uint4*)(&Bs[ar][ac]) = *(const uint4*)(Brow + k0);
    __syncthreads();
    short8 a0 = *(const short8*)(&As[wm + l16][quad * 8]);
    short8 a1 = *(const short8*)(&As[wm + 16 + l16][quad * 8]);
    short8 b0 = *(const short8*)(&Bs[wn + l16][quad * 8]);
    short8 b1 = *(const short8*)(&Bs[wn + 16 + l16][quad * 8]);
    acc[0][0] = __builtin_amdgcn_mfma_f32_16x16x32_bf16(a0, b0, acc[0][0], 0, 0, 0);
    acc[0][1] = __builtin_amdgcn_mfma_f32_16x16x32_bf16(a0, b1, acc[0][1], 0, 0, 0);
    acc[1][0] = __builtin_amdgcn_mfma_f32_16x16x32_bf16(a1, b0, acc[1][0], 0, 0, 0);
    acc[1][1] = __builtin_amdgcn_mfma_f32_16x16x32_bf16(a1, b1, acc[1][1], 0, 0, 0);
    __syncthreads();
  }
  for (int i = 0; i < 2; i++) {
    for (int j = 0; j < 2; j++) {
      int col = n0 + wn + j * 16 + l16;
      float bv = bias ? bias[col] : 0.f;
      for (int r = 0; r < 4; r++) {
        int row = m0 + wm + i * 16 + quad * 4 + r;
        float v = acc[i][j][r] + bv;
        if (gelu) v = 0.5f * v * (1.f + erff(v * 0.70710678118f));
        size_t o = (size_t)row * Nd + col;
        if (res) v += res[o];
        if (outBf16) ((__hip_bfloat16*)out)[o] = f2b(v);
        else         ((float*)out)[o] = v;
      }
    }
  }
}

// ---------------- MFMA cross-attention (flash-style online softmax) --------
// grid (kN/64, kB*kH) = (64, 32), block 256 = 4 waves.
// Wave w owns q-rows [q0+16w, q0+16w+16). Loop over 8 K-tiles of 64 keys.
// Frag maps (m89/m91-verified, same as gemm_bf16):
//   A: lane holds A[m=l16][k=quad*8+j]; B: B[k=quad*8+j][n=l16]
//   C/D: reg r -> row=quad*4+r, col=l16  (row reductions = shfl over low 4 bits)
__global__ __launch_bounds__(256) void cross_attn_mfma(
    const __hip_bfloat16* __restrict__ Qb,   // [B*N][1024]
    const __hip_bfloat16* __restrict__ KVb,  // [B*M][2048] (k | v)
    const int* __restrict__ cmask,           // [B*M]
    __hip_bfloat16* __restrict__ Ob) {       // [B*N][1024]
  // V tiles in packed B-frag layout [kb=key>>3][n=d][j=key&7], double-buffered.
  __shared__ __align__(16) __hip_bfloat16 Vbf[2][8][64][8];   // 16 KB
  // Per-wave P in packed A-frag layout [kb=key>>3][m=qrow][j=key&7].
  __shared__ __align__(16) __hip_bfloat16 Paf[4][8][16][8];   // 8 KB
  int b = blockIdx.y >> 4, h = blockIdx.y & 15;
  int q0 = blockIdx.x * 64;
  int tid = threadIdx.x, wave = tid >> 6, lane = tid & 63;
  int l16 = lane & 15, quad = lane >> 4;

  // Q A-frags, loaded once from global (rows are L2/L1-warm, 16B/lane).
  const __hip_bfloat16* qrow =
      Qb + (size_t)(b * kN + q0 + wave * 16 + l16) * 1024 + h * 64 + quad * 8;
  short8 qf0 = *(const short8*)qrow;
  short8 qf1 = *(const short8*)(qrow + 32);

  floatx4 of[4] = {};                 // O accum: df frags of 16x16
  float Mr[4] = {-1e30f, -1e30f, -1e30f, -1e30f};
  float Lr[4] = {};

  // staging indices: thread t loads key16 = t>>2 (64 keys), d0 = (t&3)*16
  int skey = tid >> 2, sd0 = (tid & 3) * 16;

  for (int kt = 0; kt < 8; kt++) {
    int buf = kt & 1;
    {  // stage V tile kt -> Vbf[buf] (packed B-frag layout)
      const __hip_bfloat16* src =
          KVb + (size_t)(b * kM + kt * 64 + skey) * 2048 + 1024 + h * 64 + sd0;
      short8 v0 = *(const short8*)src;
      short8 v1 = *(const short8*)(src + 8);
      int kb = skey >> 3, kj = skey & 7;
      #pragma unroll
      for (int j = 0; j < 8; j++) {
        Vbf[buf][kb][sd0 + j][kj] = __hip_bfloat16(__hip_bfloat16_raw{(unsigned short)v0[j]});
        Vbf[buf][kb][sd0 + 8 + j][kj] = __hip_bfloat16(__hip_bfloat16_raw{(unsigned short)v1[j]});
      }
    }
    __syncthreads();  // [stage; bar; compute] + dbuf => race-free, 1 bar/tile

    // ---- QK^T: S[16 x 64] per wave, 4 nf frags x 2 k-steps
    floatx4 sf[4];
    #pragma unroll
    for (int nf = 0; nf < 4; nf++) {
      const __hip_bfloat16* krow =
          KVb + (size_t)(b * kM + kt * 64 + nf * 16 + l16) * 2048 + h * 64 + quad * 8;
      short8 kf0 = *(const short8*)krow;
      short8 kf1 = *(const short8*)(krow + 32);
      floatx4 z = {};
      z = __builtin_amdgcn_mfma_f32_16x16x32_bf16(qf0, kf0, z, 0, 0, 0);
      z = __builtin_amdgcn_mfma_f32_16x16x32_bf16(qf1, kf1, z, 0, 0, 0);
      sf[nf] = z;
    }

    // ---- mask + scale
    float sv[4][4];
    #pragma unroll
    for (int nf = 0; nf < 4; nf++) {
      int mk = cmask[b * kM + kt * 64 + nf * 16 + l16];
      #pragma unroll
      for (int r = 0; r < 4; r++)
        sv[nf][r] = mk ? sf[nf][r] * kSCALE : kNEG;
    }
    // ---- online softmax (rows quad*4+r; reduce across l16 within quad)
    float mx[4];
    #pragma unroll
    for (int r = 0; r < 4; r++) {
      float m = fmaxf(fmaxf(sv[0][r], sv[1][r]), fmaxf(sv[2][r], sv[3][r]));
      #pragma unroll
      for (int off = 1; off < 16; off <<= 1) m = fmaxf(m, __shfl_xor(m, off));
      mx[r] = m;
    }
    float alpha[4], Mn[4];
    #pragma unroll
    for (int r = 0; r < 4; r++) {
      Mn[r] = fmaxf(Mr[r], mx[r]);
      alpha[r] = __expf(Mr[r] - Mn[r]);
      Mr[r] = Mn[r];
    }
    float p[4][4];
    float rsum[4];
    #pragma unroll
    for (int r = 0; r < 4; r++) {
      float s = 0.f;
      #pragma unroll
      for (int nf = 0; nf < 4; nf++) {
        float e = __expf(sv[nf][r] - Mn[r]);
        p[nf][r] = e; s += e;
      }
      #pragma unroll
      for (int off = 1; off < 16; off <<= 1) s += __shfl_xor(s, off);
      rsum[r] = s;
    }
    #pragma unroll
    for (int r = 0; r < 4; r++) Lr[r] = Lr[r] * alpha[r] + rsum[r];
    #pragma unroll
    for (int df = 0; df < 4; df++)
      #pragma unroll
      for (int r = 0; r < 4; r++) of[df][r] *= alpha[r];

    // ---- P (C-layout regs) -> Paf (A-frag layout) in LDS, per-wave private
    #pragma unroll
    for (int nf = 0; nf < 4; nf++) {
      int col = nf * 16 + l16;
      int kb = col >> 3, kj = col & 7;
      #pragma unroll
      for (int r = 0; r < 4; r++)
        Paf[wave][kb][quad * 4 + r][kj] = f2b(p[nf][r]);
    }
    __builtin_amdgcn_s_waitcnt(0);  // drain lgkm before same-wave readback
    // (compiler also inserts waits on the dependent ds_reads below)

    // ---- PV: O += P @ V_tile
    short8 pf0 = *(const short8*)(&Paf[wave][quad][l16][0]);
    short8 pf1 = *(const short8*)(&Paf[wave][quad + 4][l16][0]);
    #pragma unroll
    for (int df = 0; df < 4; df++) {
      short8 vf0 = *(const short8*)(&Vbf[buf][quad][df * 16 + l16][0]);
      short8 vf1 = *(const short8*)(&Vbf[buf][quad + 4][df * 16 + l16][0]);
      of[df] = __builtin_amdgcn_mfma_f32_16x16x32_bf16(pf0, vf0, of[df], 0, 0, 0);
      of[df] = __builtin_amdgcn_mfma_f32_16x16x32_bf16(pf1, vf1, of[df], 0, 0, 0);
    }
  }

  // ---- epilogue: O /= L, write bf16
  #pragma unroll
  for (int df = 0; df < 4; df++) {
    #pragma unroll
    for (int r = 0; r < 4; r++) {
      int row = q0 + wave * 16 + quad * 4 + r;
      float v = of[df][r] / Lr[r];
      Ob[(size_t)(b * kN + row) * 1024 + h * 64 + df * 16 + l16] = f2b(v);
    }
  }
}

// ---------------- temporal attention (with RoPE) ----------------
__global__ __launch_bounds__(64) void temporal_attn(
    const __hip_bfloat16* __restrict__ QKVb,  // [B*T*L][1536] (q|k|v)
    const float* __restrict__ rope,           // [T][32] fp32
    const int* __restrict__ amask,            // [B*T]
    __hip_bfloat16* __restrict__ Otb) {       // [B*T*L][512]
  __shared__ float qs[16][65], ks[16][65], vs[16][65];
  __shared__ float Ps[16][17];
  int idx = blockIdx.x;
  int h = idx & 7, l = (idx >> 3) & 255, b = idx >> 11;
  int lane = threadIdx.x;

  {
    int tr = lane >> 2, c0 = (lane & 3) * 16;
    size_t rowbase = ((size_t)(b * kT + tr) * kL + l) * 1536 + h * 64;
    for (int j = 0; j < 16; j++) {
      qs[tr][c0 + j] = b2f(QKVb[rowbase + c0 + j]) * kSCALE;
      ks[tr][c0 + j] = b2f(QKVb[rowbase + 512 + c0 + j]);
      vs[tr][c0 + j] = b2f(QKVb[rowbase + 1024 + c0 + j]);
    }
  }
  __syncthreads();
  {
    int rt = lane >> 2, rd0 = (lane & 3) * 8;
    float nq[8], nk[8];
    for (int j = 0; j < 8; j++) {
      int d = rd0 + j;
      float ang = rope[rt * kROT + d];
      float cv = cosf(ang), sv = sinf(ang);
      float oq = (d < 16) ? -qs[rt][d + 16] : qs[rt][d - 16];
      float ok = (d < 16) ? -ks[rt][d + 16] : ks[rt][d - 16];
      nq[j] = qs[rt][d] * cv + oq * sv;
      nk[j] = ks[rt][d] * cv + ok * sv;
    }
    __syncthreads();
    for (int j = 0; j < 8; j++) { qs[rt][rd0 + j] = nq[j]; ks[rt][rd0 + j] = nk[j]; }
  }
  __syncthreads();
  {
    int tq = lane >> 2, tk0 = (lane & 3) * 4;
    float s[4] = {0, 0, 0, 0};
    for (int d = 0; d < 64; d++) {
      float qv = qs[tq][d];
      s[0] += qv * ks[tk0 + 0][d];
      s[1] += qv * ks[tk0 + 1][d];
      s[2] += qv * ks[tk0 + 2][d];
      s[3] += qv * ks[tk0 + 3][d];
    }
    for (int jj = 0; jj < 4; jj++)
      Ps[tq][tk0 + jj] = amask[b * kT + tk0 + jj] ? s[jj] : kNEG;
  }
  __syncthreads();
  if (lane < 16) {
    float mx = -1e30f;
    for (int k = 0; k < 16; k++) mx = fmaxf(mx, Ps[lane][k]);
    float sum = 0.f;
    for (int k = 0; k < 16; k++) { float p = __expf(Ps[lane][k] - mx); Ps[lane][k] = p; sum += p; }
    float inv = 1.f / sum;
    for (int k = 0; k < 16; k++) Ps[lane][k] *= inv;
  }
  __syncthreads();
  for (int tq = 0; tq < 16; tq++) {
    float acc = 0.f;
    for (int tk = 0; tk < 16; tk++) acc += Ps[tq][tk] * vs[tk][lane];
    float qm = amask[b * kT + tq] ? 1.f : 0.f;
    Otb[((size_t)(b * kT + tq) * kL + l) * 512 + h * 64 + lane] = f2b(acc * qm);
  }
}

// ---------------- launcher ----------------
extern "C" void kernel_launch(void* const* d_in, const int* in_sizes, int n_in,
                              void* d_out, int out_size, void* d_ws, size_t ws_size,
                              hipStream_t stream) {
  const float* x       = (const float*)d_in[0];
  const float* ctx     = (const float*)d_in[1];
  const float* rope    = (const float*)d_in[2];
  const float* ca_ng   = (const float*)d_in[3];
  const float* ca_nb   = (const float*)d_in[4];
  const float* ca_cng  = (const float*)d_in[5];
  const float* ca_cnb  = (const float*)d_in[6];
  const float* ca_wq   = (const float*)d_in[7];
  const float* ca_wkv  = (const float*)d_in[8];
  const float* ca_wo   = (const float*)d_in[9];
  const float* ta_ng   = (const float*)d_in[10];
  const float* ta_nb   = (const float*)d_in[11];
  const float* ta_wqkv = (const float*)d_in[12];
  const float* ta_bqkv = (const float*)d_in[13];
  const float* ta_wo   = (const float*)d_in[14];
  const float* ff_ng   = (const float*)d_in[15];
  const float* ff_nb   = (const float*)d_in[16];
  const float* ff_w1   = (const float*)d_in[17];
  const float* ff_w2   = (const float*)d_in[18];
  const unsigned char* cmraw = (const unsigned char*)d_in[19];
  const unsigned char* amraw = (const unsigned char*)d_in[20];

  char* wsc = (char*)d_ws;
  size_t off = 0;
  auto take = [&](size_t bytes) {
    char* p = wsc + off;
    off = (off + bytes + 255) & ~(size_t)255;
    return p;
  };
  __hip_bfloat16* wqT   = (__hip_bfloat16*)take((size_t)1024 * 1024 * 2);
  __hip_bfloat16* wkvT  = (__hip_bfloat16*)take((size_t)2048 * 1024 * 2);
  __hip_bfloat16* woT   = (__hip_bfloat16*)take((size_t)1024 * 1024 * 2);
  __hip_bfloat16* wqkvT = (__hip_bfloat16*)take((size_t)1536 * 1024 * 2);
  __hip_bfloat16* tawoT = (__hip_bfloat16*)take((size_t)1024 * 512 * 2);
  __hip_bfloat16* ffw1T = (__hip_bfloat16*)take((size_t)4096 * 1024 * 2);
  __hip_bfloat16* ffw2T = (__hip_bfloat16*)take((size_t)1024 * 4096 * 2);
  __hip_bfloat16* XN  = (__hip_bfloat16*)take((size_t)8192 * 1024 * 2);
  __hip_bfloat16* CN  = (__hip_bfloat16*)take((size_t)1024 * 1024 * 2);
  __hip_bfloat16* Qb  = (__hip_bfloat16*)take((size_t)8192 * 1024 * 2);
  __hip_bfloat16* KVb = (__hip_bfloat16*)take((size_t)1024 * 2048 * 2);
  __hip_bfloat16* Ob  = (__hip_bfloat16*)take((size_t)8192 * 1024 * 2);
  float*          X1  = (float*)take((size_t)8192 * 1024 * 4);
  __hip_bfloat16* Hb  = (__hip_bfloat16*)take((size_t)8192 * 4096 * 2);
  int* cmask = (int*)take((size_t)kB * kM * 4);
  int* amask = (int*)take((size_t)kB * kT * 4);
  if (off > ws_size) return;

  __hip_bfloat16* QKVb = Hb;  // [8192][1536], dead before Hb is written
  __hip_bfloat16* OTb  = Qb;  // [8192][512], Q dead after cross_attn

  auto gemm = [&](const __hip_bfloat16* A, const __hip_bfloat16* Bt,
                  const float* bias, const float* res, int gelu, void* out,
                  int outBf16, int Md, int Nd, int Kd) {
    gemm_bf16<<<dim3(Md / 64, Nd / 64), dim3(256), 0, stream>>>(
        A, Bt, bias, res, gelu, out, outBf16, Md, Nd, Kd);
  };

  mask_convert<<<dim3((kB * kM + 255) / 256), dim3(256), 0, stream>>>(cmraw, kB * kM, cmask);
  mask_convert<<<dim3(1), dim3(256), 0, stream>>>(amraw, kB * kT, amask);
  transpose_w<<<dim3(1024 / 32, 1024 / 32), dim3(256), 0, stream>>>(ca_wq, wqT, 1024, 1024);
  transpose_w<<<dim3(2048 / 32, 1024 / 32), dim3(256), 0, stream>>>(ca_wkv, wkvT, 1024, 2048);
  transpose_w<<<dim3(1024 / 32, 1024 / 32), dim3(256), 0, stream>>>(ca_wo, woT, 1024, 1024);
  transpose_w<<<dim3(1536 / 32, 1024 / 32), dim3(256), 0, stream>>>(ta_wqkv, wqkvT, 1024, 1536);
  transpose_w<<<dim3(1024 / 32, 512 / 32), dim3(256), 0, stream>>>(ta_wo, tawoT, 512, 1024);
  transpose_w<<<dim3(4096 / 32, 1024 / 32), dim3(256), 0, stream>>>(ff_w1, ffw1T, 1024, 4096);
  transpose_w<<<dim3(1024 / 32, 4096 / 32), dim3(256), 0, stream>>>(ff_w2, ffw2T, 4096, 1024);

  // cross-attention block
  ln_rows<<<dim3(8192), dim3(256), 0, stream>>>(x, ca_ng, ca_nb, XN);
  ln_rows<<<dim3(1024), dim3(256), 0, stream>>>(ctx, ca_cng, ca_cnb, CN);
  gemm(XN, wqT, nullptr, nullptr, 0, Qb, 1, 8192, 1024, 1024);
  gemm(CN, wkvT, nullptr, nullptr, 0, KVb, 1, 1024, 2048, 1024);
  cross_attn_mfma<<<dim3(kN / 64, kB * kH), dim3(256), 0, stream>>>(Qb, KVb, cmask, Ob);
  gemm(Ob, woT, nullptr, x, 0, X1, 0, 8192, 1024, 1024);

  // temporal attention block
  ln_rows<<<dim3(8192), dim3(256), 0, stream>>>(X1, ta_ng, ta_nb, XN);
  gemm(XN, wqkvT, ta_bqkv, nullptr, 0, QKVb, 1, 8192, 1536, 1024);
  temporal_attn<<<dim3(kB * kL * kHT), dim3(64), 0, stream>>>(QKVb, rope, amask, OTb);
  gemm(OTb, tawoT, nullptr, X1, 0, X1, 0, 8192, 1024, 512);

  // feed-forward block
  ln_rows<<<dim3(8192), dim3(256), 0, stream>>>(X1, ff_ng, ff_nb, XN);
  gemm(XN, ffw1T, nullptr, nullptr, 1, Hb, 1, 8192, 4096, 1024);
  gemm(Hb, ffw2T, nullptr, X1, 0, d_out, 0, 8192, 1024, 4096);
}

// Round 4
// 718.755 us; speedup vs baseline: 2.1762x; 1.1283x over previous
//
#include <hip/hip_runtime.h>
#include <hip/hip_bf16.h>
#include <stdint.h>

#define DEV static __device__ __forceinline__

// Problem constants
constexpr int kB = 2, kT = 16, kL = 256, kM = 512;
constexpr int kD = 1024, kH = 16, kDH = 64, kHT = 8, kROT = 32;
constexpr int kN = kT * kL;  // 4096 flattened seq for cross-attn
constexpr float kEPS = 1e-5f;
constexpr float kNEG = -1.0e9f;
constexpr float kSCALE = 0.125f;  // 1/sqrt(64)

typedef __attribute__((ext_vector_type(8))) short short8;   // 8 bf16 (guide §3)
typedef __attribute__((ext_vector_type(4))) float floatx4;

DEV float b2f(__hip_bfloat16 v) { return __bfloat162float(v); }
DEV __hip_bfloat16 f2b(float v) { return __float2bfloat16(v); }

// async global->LDS, 16B per lane; LDS dst = wave-uniform base + lane*16
DEV void gl2lds16(const __hip_bfloat16* g, __hip_bfloat16* l) {
  __builtin_amdgcn_global_load_lds(
      (const __attribute__((address_space(1))) void*)g,
      (__attribute__((address_space(3))) void*)l, 16, 0, 0);
}

// ---------------- mask conversion ----------------
__global__ void mask_convert(const unsigned char* __restrict__ raw, int n,
                             int* __restrict__ out) {
  int i = blockIdx.x * blockDim.x + threadIdx.x;
  if (i >= n) return;
  unsigned char b1 = raw[1], b3 = raw[3];
  int v;
  if (b1 == 0x3F) {                                    // bf16: 1.0 = 80 3F
    v = ((const unsigned short*)raw)[i] != 0;
  } else if (b3 == 0x3F) {                             // fp32: 1.0f = 00 00 80 3F
    v = ((const float*)raw)[i] != 0.0f;
  } else if (b1 == 1) {                                // bool bytes
    v = raw[i] != 0;
  } else {                                             // int32
    v = ((const int*)raw)[i] != 0;
  }
  out[i] = v;
}

// ---------------- weight transpose+downcast W[K][N] fp32 -> Wt[N][K] bf16 ----
__global__ __launch_bounds__(256) void transpose_w(
    const float* __restrict__ W, __hip_bfloat16* __restrict__ Wt,
    int Kd, int Nd) {
  __shared__ float tile[32][33];
  int n0 = blockIdx.x * 32, k0 = blockIdx.y * 32;
  int tx = threadIdx.x & 31, ty = threadIdx.x >> 5;
  for (int i = 0; i < 32; i += 8)
    tile[ty + i][tx] = W[(size_t)(k0 + ty + i) * Nd + n0 + tx];
  __syncthreads();
  for (int i = 0; i < 32; i += 8)
    Wt[(size_t)(n0 + ty + i) * Kd + k0 + tx] = f2b(tile[tx][ty + i]);
}

// ---------------- LayerNorm over D=1024 fp32 in, bf16 out; 1 block/row -----
__global__ __launch_bounds__(256) void ln_rows(
    const float* __restrict__ X, const float* __restrict__ g,
    const float* __restrict__ bb, __hip_bfloat16* __restrict__ out) {
  int row = blockIdx.x, tid = threadIdx.x;
  const float* xr = X + (size_t)row * kD;
  float v[4], s = 0.f, s2 = 0.f;
  for (int j = 0; j < 4; j++) {
    float t = xr[tid + j * 256];
    v[j] = t; s += t; s2 += t * t;
  }
  for (int off = 32; off; off >>= 1) {
    s += __shfl_down(s, off);
    s2 += __shfl_down(s2, off);
  }
  __shared__ float rs[4], rs2[4];
  if ((tid & 63) == 0) { rs[tid >> 6] = s; rs2[tid >> 6] = s2; }
  __syncthreads();
  float ts = rs[0] + rs[1] + rs[2] + rs[3];
  float ts2 = rs2[0] + rs2[1] + rs2[2] + rs2[3];
  float mu = ts * (1.f / kD);
  float var = ts2 * (1.f / kD) - mu * mu;
  float rstd = rsqrtf(var + kEPS);
  for (int j = 0; j < 4; j++) {
    int idx = tid + j * 256;
    float o = (v[j] - mu) * rstd * g[idx] + bb[idx];
    out[(size_t)row * kD + idx] = f2b(o);
  }
}

// ---------------- MFMA GEMM, m97 structure ----------------
// 128x128 block tile, BK=32, 4 waves in 2x2 (each 64x64 = 4x4 frags of
// 16x16x32). Staging via global_load_lds width=16: thread t=w*64+lane covers
// LDS bytes w*1024 + lane*16 (wave-uniform base + lane*16 contract, m104).
// LDS rows unpadded 32 elems (64 B) -> 2-way bank aliasing on ds_read_b128,
// free per m136; identical layout to m97 (874 TF @4096^3).
__global__ __launch_bounds__(256) void gemm_bf16(
    const __hip_bfloat16* __restrict__ A,    // [Md][Kd]
    const __hip_bfloat16* __restrict__ Bt,   // [Nd][Kd]
    const float* __restrict__ bias,          // [Nd] or null
    const float* __restrict__ res,           // [Md][Nd] fp32 or null
    int gelu,
    void* __restrict__ out, int outBf16,
    int Md, int Nd, int Kd) {
  __shared__ __align__(16) __hip_bfloat16 As[128 * 32];  // 8 KB
  __shared__ __align__(16) __hip_bfloat16 Bs[128 * 32];  // 8 KB
  int m0 = blockIdx.x * 128, n0 = blockIdx.y * 128;
  int tid = threadIdx.x, wave = tid >> 6, lane = tid & 63;
  int l16 = lane & 15, quad = lane >> 4;
  int wm = (wave >> 1) * 64, wn = (wave & 1) * 64;

  // staging addresses: wave w, lane -> row w*16 + (lane>>2), col (lane&3)*8
  int srow = wave * 16 + (lane >> 2);
  int scol = (lane & 3) * 8;
  const __hip_bfloat16* Ag0 = A + (size_t)(m0 + srow) * Kd + scol;
  const __hip_bfloat16* Ag1 = A + (size_t)(m0 + 64 + srow) * Kd + scol;
  const __hip_bfloat16* Bg0 = Bt + (size_t)(n0 + srow) * Kd + scol;
  const __hip_bfloat16* Bg1 = Bt + (size_t)(n0 + 64 + srow) * Kd + scol;
  __hip_bfloat16* Al0 = As + wave * 16 * 32;
  __hip_bfloat16* Al1 = As + (64 + wave * 16) * 32;
  __hip_bfloat16* Bl0 = Bs + wave * 16 * 32;
  __hip_bfloat16* Bl1 = Bs + (64 + wave * 16) * 32;

  floatx4 acc[4][4] = {};
  for (int k0 = 0; k0 < Kd; k0 += 32) {
    gl2lds16(Ag0 + k0, Al0);
    gl2lds16(Ag1 + k0, Al1);
    gl2lds16(Bg0 + k0, Bl0);
    gl2lds16(Bg1 + k0, Bl1);
    __syncthreads();  // compiler drains vmcnt before s_barrier
    short8 af[4], bf[4];
    #pragma unroll
    for (int mf = 0; mf < 4; mf++)
      af[mf] = *(const short8*)(&As[(wm + mf * 16 + l16) * 32 + quad * 8]);
    #pragma unroll
    for (int nf = 0; nf < 4; nf++)
      bf[nf] = *(const short8*)(&Bs[(wn + nf * 16 + l16) * 32 + quad * 8]);
    #pragma unroll
    for (int mf = 0; mf < 4; mf++)
      #pragma unroll
      for (int nf = 0; nf < 4; nf++)
        acc[mf][nf] = __builtin_amdgcn_mfma_f32_16x16x32_bf16(
            af[mf], bf[nf], acc[mf][nf], 0, 0, 0);
    __syncthreads();
  }
  // epilogue: D-layout reg r -> row=quad*4+r, col=l16
  #pragma unroll
  for (int mf = 0; mf < 4; mf++) {
    #pragma unroll
    for (int nf = 0; nf < 4; nf++) {
      int col = n0 + wn + nf * 16 + l16;
      float bv = bias ? bias[col] : 0.f;
      #pragma unroll
      for (int r = 0; r < 4; r++) {
        int row = m0 + wm + mf * 16 + quad * 4 + r;
        float v = acc[mf][nf][r] + bv;
        if (gelu) v = 0.5f * v * (1.f + erff(v * 0.70710678118f));
        size_t o = (size_t)row * Nd + col;
        if (res) v += res[o];
        if (outBf16) ((__hip_bfloat16*)out)[o] = f2b(v);
        else         ((float*)out)[o] = v;
      }
    }
  }
}

// ---------------- MFMA cross-attention (flash-style online softmax) --------
__global__ __launch_bounds__(256) void cross_attn_mfma(
    const __hip_bfloat16* __restrict__ Qb,   // [B*N][1024]
    const __hip_bfloat16* __restrict__ KVb,  // [B*M][2048] (k | v)
    const int* __restrict__ cmask,           // [B*M]
    __hip_bfloat16* __restrict__ Ob) {       // [B*N][1024]
  __shared__ __align__(16) __hip_bfloat16 Vbf[2][8][64][8];   // 16 KB
  __shared__ __align__(16) __hip_bfloat16 Paf[4][8][16][8];   // 8 KB
  int b = blockIdx.y >> 4, h = blockIdx.y & 15;
  int q0 = blockIdx.x * 64;
  int tid = threadIdx.x, wave = tid >> 6, lane = tid & 63;
  int l16 = lane & 15, quad = lane >> 4;

  const __hip_bfloat16* qrow =
      Qb + (size_t)(b * kN + q0 + wave * 16 + l16) * 1024 + h * 64 + quad * 8;
  short8 qf0 = *(const short8*)qrow;
  short8 qf1 = *(const short8*)(qrow + 32);

  floatx4 of[4] = {};
  float Mr[4] = {-1e30f, -1e30f, -1e30f, -1e30f};
  float Lr[4] = {};

  int skey = tid >> 2, sd0 = (tid & 3) * 16;

  for (int kt = 0; kt < 8; kt++) {
    int buf = kt & 1;
    {
      const __hip_bfloat16* src =
          KVb + (size_t)(b * kM + kt * 64 + skey) * 2048 + 1024 + h * 64 + sd0;
      short8 v0 = *(const short8*)src;
      short8 v1 = *(const short8*)(src + 8);
      int kb = skey >> 3, kj = skey & 7;
      #pragma unroll
      for (int j = 0; j < 8; j++) {
        Vbf[buf][kb][sd0 + j][kj] = __hip_bfloat16(__hip_bfloat16_raw{(unsigned short)v0[j]});
        Vbf[buf][kb][sd0 + 8 + j][kj] = __hip_bfloat16(__hip_bfloat16_raw{(unsigned short)v1[j]});
      }
    }
    __syncthreads();

    floatx4 sf[4];
    #pragma unroll
    for (int nf = 0; nf < 4; nf++) {
      const __hip_bfloat16* krow =
          KVb + (size_t)(b * kM + kt * 64 + nf * 16 + l16) * 2048 + h * 64 + quad * 8;
      short8 kf0 = *(const short8*)krow;
      short8 kf1 = *(const short8*)(krow + 32);
      floatx4 z = {};
      z = __builtin_amdgcn_mfma_f32_16x16x32_bf16(qf0, kf0, z, 0, 0, 0);
      z = __builtin_amdgcn_mfma_f32_16x16x32_bf16(qf1, kf1, z, 0, 0, 0);
      sf[nf] = z;
    }

    float sv[4][4];
    #pragma unroll
    for (int nf = 0; nf < 4; nf++) {
      int mk = cmask[b * kM + kt * 64 + nf * 16 + l16];
      #pragma unroll
      for (int r = 0; r < 4; r++)
        sv[nf][r] = mk ? sf[nf][r] * kSCALE : kNEG;
    }
    float mx[4];
    #pragma unroll
    for (int r = 0; r < 4; r++) {
      float m = fmaxf(fmaxf(sv[0][r], sv[1][r]), fmaxf(sv[2][r], sv[3][r]));
      #pragma unroll
      for (int off = 1; off < 16; off <<= 1) m = fmaxf(m, __shfl_xor(m, off));
      mx[r] = m;
    }
    float alpha[4], Mn[4];
    #pragma unroll
    for (int r = 0; r < 4; r++) {
      Mn[r] = fmaxf(Mr[r], mx[r]);
      alpha[r] = __expf(Mr[r] - Mn[r]);
      Mr[r] = Mn[r];
    }
    float p[4][4];
    float rsum[4];
    #pragma unroll
    for (int r = 0; r < 4; r++) {
      float s = 0.f;
      #pragma unroll
      for (int nf = 0; nf < 4; nf++) {
        float e = __expf(sv[nf][r] - Mn[r]);
        p[nf][r] = e; s += e;
      }
      #pragma unroll
      for (int off = 1; off < 16; off <<= 1) s += __shfl_xor(s, off);
      rsum[r] = s;
    }
    #pragma unroll
    for (int r = 0; r < 4; r++) Lr[r] = Lr[r] * alpha[r] + rsum[r];
    #pragma unroll
    for (int df = 0; df < 4; df++)
      #pragma unroll
      for (int r = 0; r < 4; r++) of[df][r] *= alpha[r];

    #pragma unroll
    for (int nf = 0; nf < 4; nf++) {
      int col = nf * 16 + l16;
      int kb = col >> 3, kj = col & 7;
      #pragma unroll
      for (int r = 0; r < 4; r++)
        Paf[wave][kb][quad * 4 + r][kj] = f2b(p[nf][r]);
    }
    __builtin_amdgcn_s_waitcnt(0);

    short8 pf0 = *(const short8*)(&Paf[wave][quad][l16][0]);
    short8 pf1 = *(const short8*)(&Paf[wave][quad + 4][l16][0]);
    #pragma unroll
    for (int df = 0; df < 4; df++) {
      short8 vf0 = *(const short8*)(&Vbf[buf][quad][df * 16 + l16][0]);
      short8 vf1 = *(const short8*)(&Vbf[buf][quad + 4][df * 16 + l16][0]);
      of[df] = __builtin_amdgcn_mfma_f32_16x16x32_bf16(pf0, vf0, of[df], 0, 0, 0);
      of[df] = __builtin_amdgcn_mfma_f32_16x16x32_bf16(pf1, vf1, of[df], 0, 0, 0);
    }
  }

  #pragma unroll
  for (int df = 0; df < 4; df++) {
    #pragma unroll
    for (int r = 0; r < 4; r++) {
      int row = q0 + wave * 16 + quad * 4 + r;
      float v = of[df][r] / Lr[r];
      Ob[(size_t)(b * kN + row) * 1024 + h * 64 + df * 16 + l16] = f2b(v);
    }
  }
}

// ---------------- temporal attention (with RoPE) ----------------
__global__ __launch_bounds__(64) void temporal_attn(
    const __hip_bfloat16* __restrict__ QKVb,  // [B*T*L][1536] (q|k|v)
    const float* __restrict__ rope,           // [T][32] fp32
    const int* __restrict__ amask,            // [B*T]
    __hip_bfloat16* __restrict__ Otb) {       // [B*T*L][512]
  __shared__ float qs[16][65], ks[16][65], vs[16][65];
  __shared__ float Ps[16][17];
  int idx = blockIdx.x;
  int h = idx & 7, l = (idx >> 3) & 255, b = idx >> 11;
  int lane = threadIdx.x;

  {
    int tr = lane >> 2, c0 = (lane & 3) * 16;
    size_t rowbase = ((size_t)(b * kT + tr) * kL + l) * 1536 + h * 64;
    for (int j = 0; j < 16; j++) {
      qs[tr][c0 + j] = b2f(QKVb[rowbase + c0 + j]) * kSCALE;
      ks[tr][c0 + j] = b2f(QKVb[rowbase + 512 + c0 + j]);
      vs[tr][c0 + j] = b2f(QKVb[rowbase + 1024 + c0 + j]);
    }
  }
  __syncthreads();
  {
    int rt = lane >> 2, rd0 = (lane & 3) * 8;
    float nq[8], nk[8];
    for (int j = 0; j < 8; j++) {
      int d = rd0 + j;
      float ang = rope[rt * kROT + d];
      float cv = cosf(ang), sv = sinf(ang);
      float oq = (d < 16) ? -qs[rt][d + 16] : qs[rt][d - 16];
      float ok = (d < 16) ? -ks[rt][d + 16] : ks[rt][d - 16];
      nq[j] = qs[rt][d] * cv + oq * sv;
      nk[j] = ks[rt][d] * cv + ok * sv;
    }
    __syncthreads();
    for (int j = 0; j < 8; j++) { qs[rt][rd0 + j] = nq[j]; ks[rt][rd0 + j] = nk[j]; }
  }
  __syncthreads();
  {
    int tq = lane >> 2, tk0 = (lane & 3) * 4;
    float s[4] = {0, 0, 0, 0};
    for (int d = 0; d < 64; d++) {
      float qv = qs[tq][d];
      s[0] += qv * ks[tk0 + 0][d];
      s[1] += qv * ks[tk0 + 1][d];
      s[2] += qv * ks[tk0 + 2][d];
      s[3] += qv * ks[tk0 + 3][d];
    }
    for (int jj = 0; jj < 4; jj++)
      Ps[tq][tk0 + jj] = amask[b * kT + tk0 + jj] ? s[jj] : kNEG;
  }
  __syncthreads();
  if (lane < 16) {
    float mx = -1e30f;
    for (int k = 0; k < 16; k++) mx = fmaxf(mx, Ps[lane][k]);
    float sum = 0.f;
    for (int k = 0; k < 16; k++) { float p = __expf(Ps[lane][k] - mx); Ps[lane][k] = p; sum += p; }
    float inv = 1.f / sum;
    for (int k = 0; k < 16; k++) Ps[lane][k] *= inv;
  }
  __syncthreads();
  for (int tq = 0; tq < 16; tq++) {
    float acc = 0.f;
    for (int tk = 0; tk < 16; tk++) acc += Ps[tq][tk] * vs[tk][lane];
    float qm = amask[b * kT + tq] ? 1.f : 0.f;
    Otb[((size_t)(b * kT + tq) * kL + l) * 512 + h * 64 + lane] = f2b(acc * qm);
  }
}

// ---------------- launcher ----------------
extern "C" void kernel_launch(void* const* d_in, const int* in_sizes, int n_in,
                              void* d_out, int out_size, void* d_ws, size_t ws_size,
                              hipStream_t stream) {
  const float* x       = (const float*)d_in[0];
  const float* ctx     = (const float*)d_in[1];
  const float* rope    = (const float*)d_in[2];
  const float* ca_ng   = (const float*)d_in[3];
  const float* ca_nb   = (const float*)d_in[4];
  const float* ca_cng  = (const float*)d_in[5];
  const float* ca_cnb  = (const float*)d_in[6];
  const float* ca_wq   = (const float*)d_in[7];
  const float* ca_wkv  = (const float*)d_in[8];
  const float* ca_wo   = (const float*)d_in[9];
  const float* ta_ng   = (const float*)d_in[10];
  const float* ta_nb   = (const float*)d_in[11];
  const float* ta_wqkv = (const float*)d_in[12];
  const float* ta_bqkv = (const float*)d_in[13];
  const float* ta_wo   = (const float*)d_in[14];
  const float* ff_ng   = (const float*)d_in[15];
  const float* ff_nb   = (const float*)d_in[16];
  const float* ff_w1   = (const float*)d_in[17];
  const float* ff_w2   = (const float*)d_in[18];
  const unsigned char* cmraw = (const unsigned char*)d_in[19];
  const unsigned char* amraw = (const unsigned char*)d_in[20];

  char* wsc = (char*)d_ws;
  size_t off = 0;
  auto take = [&](size_t bytes) {
    char* p = wsc + off;
    off = (off + bytes + 255) & ~(size_t)255;
    return p;
  };
  __hip_bfloat16* wqT   = (__hip_bfloat16*)take((size_t)1024 * 1024 * 2);
  __hip_bfloat16* wkvT  = (__hip_bfloat16*)take((size_t)2048 * 1024 * 2);
  __hip_bfloat16* woT   = (__hip_bfloat16*)take((size_t)1024 * 1024 * 2);
  __hip_bfloat16* wqkvT = (__hip_bfloat16*)take((size_t)1536 * 1024 * 2);
  __hip_bfloat16* tawoT = (__hip_bfloat16*)take((size_t)1024 * 512 * 2);
  __hip_bfloat16* ffw1T = (__hip_bfloat16*)take((size_t)4096 * 1024 * 2);
  __hip_bfloat16* ffw2T = (__hip_bfloat16*)take((size_t)1024 * 4096 * 2);
  __hip_bfloat16* XN  = (__hip_bfloat16*)take((size_t)8192 * 1024 * 2);
  __hip_bfloat16* CN  = (__hip_bfloat16*)take((size_t)1024 * 1024 * 2);
  __hip_bfloat16* Qb  = (__hip_bfloat16*)take((size_t)8192 * 1024 * 2);
  __hip_bfloat16* KVb = (__hip_bfloat16*)take((size_t)1024 * 2048 * 2);
  __hip_bfloat16* Ob  = (__hip_bfloat16*)take((size_t)8192 * 1024 * 2);
  float*          X1  = (float*)take((size_t)8192 * 1024 * 4);
  __hip_bfloat16* Hb  = (__hip_bfloat16*)take((size_t)8192 * 4096 * 2);
  int* cmask = (int*)take((size_t)kB * kM * 4);
  int* amask = (int*)take((size_t)kB * kT * 4);
  if (off > ws_size) return;

  __hip_bfloat16* QKVb = Hb;  // [8192][1536], dead before Hb is written
  __hip_bfloat16* OTb  = Qb;  // [8192][512], Q dead after cross_attn

  auto gemm = [&](const __hip_bfloat16* A, const __hip_bfloat16* Bt,
                  const float* bias, const float* res, int gelu, void* out,
                  int outBf16, int Md, int Nd, int Kd) {
    gemm_bf16<<<dim3(Md / 128, Nd / 128), dim3(256), 0, stream>>>(
        A, Bt, bias, res, gelu, out, outBf16, Md, Nd, Kd);
  };

  mask_convert<<<dim3((kB * kM + 255) / 256), dim3(256), 0, stream>>>(cmraw, kB * kM, cmask);
  mask_convert<<<dim3(1), dim3(256), 0, stream>>>(amraw, kB * kT, amask);
  transpose_w<<<dim3(1024 / 32, 1024 / 32), dim3(256), 0, stream>>>(ca_wq, wqT, 1024, 1024);
  transpose_w<<<dim3(2048 / 32, 1024 / 32), dim3(256), 0, stream>>>(ca_wkv, wkvT, 1024, 2048);
  transpose_w<<<dim3(1024 / 32, 1024 / 32), dim3(256), 0, stream>>>(ca_wo, woT, 1024, 1024);
  transpose_w<<<dim3(1536 / 32, 1024 / 32), dim3(256), 0, stream>>>(ta_wqkv, wqkvT, 1024, 1536);
  transpose_w<<<dim3(1024 / 32, 512 / 32), dim3(256), 0, stream>>>(ta_wo, tawoT, 512, 1024);
  transpose_w<<<dim3(4096 / 32, 1024 / 32), dim3(256), 0, stream>>>(ff_w1, ffw1T, 1024, 4096);
  transpose_w<<<dim3(1024 / 32, 4096 / 32), dim3(256), 0, stream>>>(ff_w2, ffw2T, 4096, 1024);

  // cross-attention block
  ln_rows<<<dim3(8192), dim3(256), 0, stream>>>(x, ca_ng, ca_nb, XN);
  ln_rows<<<dim3(1024), dim3(256), 0, stream>>>(ctx, ca_cng, ca_cnb, CN);
  gemm(XN, wqT, nullptr, nullptr, 0, Qb, 1, 8192, 1024, 1024);
  gemm(CN, wkvT, nullptr, nullptr, 0, KVb, 1, 1024, 2048, 1024);
  cross_attn_mfma<<<dim3(kN / 64, kB * kH), dim3(256), 0, stream>>>(Qb, KVb, cmask, Ob);
  gemm(Ob, woT, nullptr, x, 0, X1, 0, 8192, 1024, 1024);

  // temporal attention block
  ln_rows<<<dim3(8192), dim3(256), 0, stream>>>(X1, ta_ng, ta_nb, XN);
  gemm(XN, wqkvT, ta_bqkv, nullptr, 0, QKVb, 1, 8192, 1536, 1024);
  temporal_attn<<<dim3(kB * kL * kHT), dim3(64), 0, stream>>>(QKVb, rope, amask, OTb);
  gemm(OTb, tawoT, nullptr, X1, 0, X1, 0, 8192, 1024, 512);

  // feed-forward block
  ln_rows<<<dim3(8192), dim3(256), 0, stream>>>(X1, ff_ng, ff_nb, XN);
  gemm(XN, ffw1T, nullptr, nullptr, 1, Hb, 1, 8192, 4096, 1024);
  gemm(Hb, ffw2T, nullptr, X1, 0, d_out, 0, 8192, 1024, 4096);
}

// Round 5
// 707.868 us; speedup vs baseline: 2.2096x; 1.0154x over previous
//
#include <hip/hip_runtime.h>
#include <hip/hip_bf16.h>
#include <stdint.h>

#define DEV static __device__ __forceinline__

// Problem constants
constexpr int kB = 2, kT = 16, kL = 256, kM = 512;
constexpr int kD = 1024, kH = 16, kDH = 64, kHT = 8, kROT = 32;
constexpr int kN = kT * kL;  // 4096 flattened seq for cross-attn
constexpr float kEPS = 1e-5f;
constexpr float kNEG = -1.0e9f;
constexpr float kSCALE = 0.125f;  // 1/sqrt(64)

typedef __attribute__((ext_vector_type(8))) short short8;   // 8 bf16 (guide §3)
typedef __attribute__((ext_vector_type(4))) float floatx4;

DEV float b2f(__hip_bfloat16 v) { return __bfloat162float(v); }
DEV __hip_bfloat16 f2b(float v) { return __float2bfloat16(v); }
DEV float s2f(short x) {
  __hip_bfloat16_raw r; r.x = (unsigned short)x;
  return __bfloat162float(__hip_bfloat16(r));
}

// async global->LDS, 16B per lane; LDS dst = wave-uniform base + lane*16
DEV void gl2lds16(const __hip_bfloat16* g, __hip_bfloat16* l) {
  __builtin_amdgcn_global_load_lds(
      (const __attribute__((address_space(1))) void*)g,
      (__attribute__((address_space(3))) void*)l, 16, 0, 0);
}

// ---------------- mask conversion ----------------
__global__ void mask_convert(const unsigned char* __restrict__ raw, int n,
                             int* __restrict__ out) {
  int i = blockIdx.x * blockDim.x + threadIdx.x;
  if (i >= n) return;
  unsigned char b1 = raw[1], b3 = raw[3];
  int v;
  if (b1 == 0x3F) {                                    // bf16: 1.0 = 80 3F
    v = ((const unsigned short*)raw)[i] != 0;
  } else if (b3 == 0x3F) {                             // fp32: 1.0f = 00 00 80 3F
    v = ((const float*)raw)[i] != 0.0f;
  } else if (b1 == 1) {                                // bool bytes
    v = raw[i] != 0;
  } else {                                             // int32
    v = ((const int*)raw)[i] != 0;
  }
  out[i] = v;
}

// ---------------- weight transpose+downcast W[K][N] fp32 -> Wt[N][K] bf16 ----
__global__ __launch_bounds__(256) void transpose_w(
    const float* __restrict__ W, __hip_bfloat16* __restrict__ Wt,
    int Kd, int Nd) {
  __shared__ float tile[32][33];
  int n0 = blockIdx.x * 32, k0 = blockIdx.y * 32;
  int tx = threadIdx.x & 31, ty = threadIdx.x >> 5;
  for (int i = 0; i < 32; i += 8)
    tile[ty + i][tx] = W[(size_t)(k0 + ty + i) * Nd + n0 + tx];
  __syncthreads();
  for (int i = 0; i < 32; i += 8)
    Wt[(size_t)(n0 + ty + i) * Kd + k0 + tx] = f2b(tile[tx][ty + i]);
}

// ---------------- LayerNorm over D=1024 fp32 in, bf16 out; 1 block/row -----
// float4 loads, ushort4 packed bf16 stores (4 contiguous elems per thread).
__global__ __launch_bounds__(256) void ln_rows(
    const float* __restrict__ X, const float* __restrict__ g,
    const float* __restrict__ bb, __hip_bfloat16* __restrict__ out) {
  int row = blockIdx.x, tid = threadIdx.x;
  float4 xv = *(const float4*)(X + (size_t)row * kD + tid * 4);
  float s = xv.x + xv.y + xv.z + xv.w;
  float s2 = xv.x * xv.x + xv.y * xv.y + xv.z * xv.z + xv.w * xv.w;
  for (int off = 32; off; off >>= 1) {
    s += __shfl_down(s, off);
    s2 += __shfl_down(s2, off);
  }
  __shared__ float rs[4], rs2[4];
  if ((tid & 63) == 0) { rs[tid >> 6] = s; rs2[tid >> 6] = s2; }
  __syncthreads();
  float ts = rs[0] + rs[1] + rs[2] + rs[3];
  float ts2 = rs2[0] + rs2[1] + rs2[2] + rs2[3];
  float mu = ts * (1.f / kD);
  float var = ts2 * (1.f / kD) - mu * mu;
  float rstd = rsqrtf(var + kEPS);
  float4 gv = *(const float4*)(g + tid * 4);
  float4 bv = *(const float4*)(bb + tid * 4);
  ushort4 o;
  o.x = __hip_bfloat16_raw(f2b((xv.x - mu) * rstd * gv.x + bv.x)).x;
  o.y = __hip_bfloat16_raw(f2b((xv.y - mu) * rstd * gv.y + bv.y)).x;
  o.z = __hip_bfloat16_raw(f2b((xv.z - mu) * rstd * gv.z + bv.z)).x;
  o.w = __hip_bfloat16_raw(f2b((xv.w - mu) * rstd * gv.w + bv.w)).x;
  *(ushort4*)(out + (size_t)row * kD + tid * 4) = o;
}

// ---------------- MFMA GEMM, m97 structure ----------------
// 128x128 block tile, BK=32, 4 waves in 2x2 (each 64x64 = 4x4 frags of
// 16x16x32). Staging via global_load_lds width=16. GELU via sigmoid form
// (exact-erf epilogue was ~half of ff1's cycles at K=1024 — round-4 PMC).
__global__ __launch_bounds__(256) void gemm_bf16(
    const __hip_bfloat16* __restrict__ A,    // [Md][Kd]
    const __hip_bfloat16* __restrict__ Bt,   // [Nd][Kd]
    const float* __restrict__ bias,          // [Nd] or null
    const float* __restrict__ res,           // [Md][Nd] fp32 or null
    int gelu,
    void* __restrict__ out, int outBf16,
    int Md, int Nd, int Kd) {
  __shared__ __align__(16) __hip_bfloat16 As[128 * 32];  // 8 KB
  __shared__ __align__(16) __hip_bfloat16 Bs[128 * 32];  // 8 KB
  int m0 = blockIdx.x * 128, n0 = blockIdx.y * 128;
  int tid = threadIdx.x, wave = tid >> 6, lane = tid & 63;
  int l16 = lane & 15, quad = lane >> 4;
  int wm = (wave >> 1) * 64, wn = (wave & 1) * 64;

  int srow = wave * 16 + (lane >> 2);
  int scol = (lane & 3) * 8;
  const __hip_bfloat16* Ag0 = A + (size_t)(m0 + srow) * Kd + scol;
  const __hip_bfloat16* Ag1 = A + (size_t)(m0 + 64 + srow) * Kd + scol;
  const __hip_bfloat16* Bg0 = Bt + (size_t)(n0 + srow) * Kd + scol;
  const __hip_bfloat16* Bg1 = Bt + (size_t)(n0 + 64 + srow) * Kd + scol;
  __hip_bfloat16* Al0 = As + wave * 16 * 32;
  __hip_bfloat16* Al1 = As + (64 + wave * 16) * 32;
  __hip_bfloat16* Bl0 = Bs + wave * 16 * 32;
  __hip_bfloat16* Bl1 = Bs + (64 + wave * 16) * 32;

  floatx4 acc[4][4] = {};
  for (int k0 = 0; k0 < Kd; k0 += 32) {
    gl2lds16(Ag0 + k0, Al0);
    gl2lds16(Ag1 + k0, Al1);
    gl2lds16(Bg0 + k0, Bl0);
    gl2lds16(Bg1 + k0, Bl1);
    __syncthreads();  // compiler drains vmcnt before s_barrier
    short8 af[4], bf[4];
    #pragma unroll
    for (int mf = 0; mf < 4; mf++)
      af[mf] = *(const short8*)(&As[(wm + mf * 16 + l16) * 32 + quad * 8]);
    #pragma unroll
    for (int nf = 0; nf < 4; nf++)
      bf[nf] = *(const short8*)(&Bs[(wn + nf * 16 + l16) * 32 + quad * 8]);
    #pragma unroll
    for (int mf = 0; mf < 4; mf++)
      #pragma unroll
      for (int nf = 0; nf < 4; nf++)
        acc[mf][nf] = __builtin_amdgcn_mfma_f32_16x16x32_bf16(
            af[mf], bf[nf], acc[mf][nf], 0, 0, 0);
    __syncthreads();
  }
  // epilogue: D-layout reg r -> row=quad*4+r, col=l16
  #pragma unroll
  for (int mf = 0; mf < 4; mf++) {
    #pragma unroll
    for (int nf = 0; nf < 4; nf++) {
      int col = n0 + wn + nf * 16 + l16;
      float bv = bias ? bias[col] : 0.f;
      #pragma unroll
      for (int r = 0; r < 4; r++) {
        int row = m0 + wm + mf * 16 + quad * 4 + r;
        float v = acc[mf][nf][r] + bv;
        if (gelu) {  // tanh-form GELU via sigmoid: x*sigma(1.5958x+0.07135x^3)
          float z = v * (1.5957691216f + 0.0713548162f * v * v);
          v = v * (1.f / (1.f + __expf(-z)));
        }
        size_t o = (size_t)row * Nd + col;
        if (res) v += res[o];
        if (outBf16) ((__hip_bfloat16*)out)[o] = f2b(v);
        else         ((float*)out)[o] = v;
      }
    }
  }
}

// ---------------- MFMA cross-attention (flash-style online softmax) --------
__global__ __launch_bounds__(256) void cross_attn_mfma(
    const __hip_bfloat16* __restrict__ Qb,   // [B*N][1024]
    const __hip_bfloat16* __restrict__ KVb,  // [B*M][2048] (k | v)
    const int* __restrict__ cmask,           // [B*M]
    __hip_bfloat16* __restrict__ Ob) {       // [B*N][1024]
  __shared__ __align__(16) __hip_bfloat16 Vbf[2][8][64][8];   // 16 KB
  __shared__ __align__(16) __hip_bfloat16 Paf[4][8][16][8];   // 8 KB
  int b = blockIdx.y >> 4, h = blockIdx.y & 15;
  int q0 = blockIdx.x * 64;
  int tid = threadIdx.x, wave = tid >> 6, lane = tid & 63;
  int l16 = lane & 15, quad = lane >> 4;

  const __hip_bfloat16* qrow =
      Qb + (size_t)(b * kN + q0 + wave * 16 + l16) * 1024 + h * 64 + quad * 8;
  short8 qf0 = *(const short8*)qrow;
  short8 qf1 = *(const short8*)(qrow + 32);

  floatx4 of[4] = {};
  float Mr[4] = {-1e30f, -1e30f, -1e30f, -1e30f};
  float Lr[4] = {};

  int skey = tid >> 2, sd0 = (tid & 3) * 16;

  for (int kt = 0; kt < 8; kt++) {
    int buf = kt & 1;
    {
      const __hip_bfloat16* src =
          KVb + (size_t)(b * kM + kt * 64 + skey) * 2048 + 1024 + h * 64 + sd0;
      short8 v0 = *(const short8*)src;
      short8 v1 = *(const short8*)(src + 8);
      int kb = skey >> 3, kj = skey & 7;
      #pragma unroll
      for (int j = 0; j < 8; j++) {
        Vbf[buf][kb][sd0 + j][kj] = __hip_bfloat16(__hip_bfloat16_raw{(unsigned short)v0[j]});
        Vbf[buf][kb][sd0 + 8 + j][kj] = __hip_bfloat16(__hip_bfloat16_raw{(unsigned short)v1[j]});
      }
    }
    __syncthreads();

    floatx4 sf[4];
    #pragma unroll
    for (int nf = 0; nf < 4; nf++) {
      const __hip_bfloat16* krow =
          KVb + (size_t)(b * kM + kt * 64 + nf * 16 + l16) * 2048 + h * 64 + quad * 8;
      short8 kf0 = *(const short8*)krow;
      short8 kf1 = *(const short8*)(krow + 32);
      floatx4 z = {};
      z = __builtin_amdgcn_mfma_f32_16x16x32_bf16(qf0, kf0, z, 0, 0, 0);
      z = __builtin_amdgcn_mfma_f32_16x16x32_bf16(qf1, kf1, z, 0, 0, 0);
      sf[nf] = z;
    }

    float sv[4][4];
    #pragma unroll
    for (int nf = 0; nf < 4; nf++) {
      int mk = cmask[b * kM + kt * 64 + nf * 16 + l16];
      #pragma unroll
      for (int r = 0; r < 4; r++)
        sv[nf][r] = mk ? sf[nf][r] * kSCALE : kNEG;
    }
    float mx[4];
    #pragma unroll
    for (int r = 0; r < 4; r++) {
      float m = fmaxf(fmaxf(sv[0][r], sv[1][r]), fmaxf(sv[2][r], sv[3][r]));
      #pragma unroll
      for (int off = 1; off < 16; off <<= 1) m = fmaxf(m, __shfl_xor(m, off));
      mx[r] = m;
    }
    float alpha[4], Mn[4];
    #pragma unroll
    for (int r = 0; r < 4; r++) {
      Mn[r] = fmaxf(Mr[r], mx[r]);
      alpha[r] = __expf(Mr[r] - Mn[r]);
      Mr[r] = Mn[r];
    }
    float p[4][4];
    float rsum[4];
    #pragma unroll
    for (int r = 0; r < 4; r++) {
      float s = 0.f;
      #pragma unroll
      for (int nf = 0; nf < 4; nf++) {
        float e = __expf(sv[nf][r] - Mn[r]);
        p[nf][r] = e; s += e;
      }
      #pragma unroll
      for (int off = 1; off < 16; off <<= 1) s += __shfl_xor(s, off);
      rsum[r] = s;
    }
    #pragma unroll
    for (int r = 0; r < 4; r++) Lr[r] = Lr[r] * alpha[r] + rsum[r];
    #pragma unroll
    for (int df = 0; df < 4; df++)
      #pragma unroll
      for (int r = 0; r < 4; r++) of[df][r] *= alpha[r];

    #pragma unroll
    for (int nf = 0; nf < 4; nf++) {
      int col = nf * 16 + l16;
      int kb = col >> 3, kj = col & 7;
      #pragma unroll
      for (int r = 0; r < 4; r++)
        Paf[wave][kb][quad * 4 + r][kj] = f2b(p[nf][r]);
    }
    __builtin_amdgcn_s_waitcnt(0);

    short8 pf0 = *(const short8*)(&Paf[wave][quad][l16][0]);
    short8 pf1 = *(const short8*)(&Paf[wave][quad + 4][l16][0]);
    #pragma unroll
    for (int df = 0; df < 4; df++) {
      short8 vf0 = *(const short8*)(&Vbf[buf][quad][df * 16 + l16][0]);
      short8 vf1 = *(const short8*)(&Vbf[buf][quad + 4][df * 16 + l16][0]);
      of[df] = __builtin_amdgcn_mfma_f32_16x16x32_bf16(pf0, vf0, of[df], 0, 0, 0);
      of[df] = __builtin_amdgcn_mfma_f32_16x16x32_bf16(pf1, vf1, of[df], 0, 0, 0);
    }
  }

  #pragma unroll
  for (int df = 0; df < 4; df++) {
    #pragma unroll
    for (int r = 0; r < 4; r++) {
      int row = q0 + wave * 16 + quad * 4 + r;
      float v = of[df][r] / Lr[r];
      Ob[(size_t)(b * kN + row) * 1024 + h * 64 + df * 16 + l16] = f2b(v);
    }
  }
}

// ---------------- temporal attention (with RoPE) ----------------
__global__ __launch_bounds__(64) void temporal_attn(
    const __hip_bfloat16* __restrict__ QKVb,  // [B*T*L][1536] (q|k|v)
    const float* __restrict__ rope,           // [T][32] fp32
    const int* __restrict__ amask,            // [B*T]
    __hip_bfloat16* __restrict__ Otb) {       // [B*T*L][512]
  __shared__ float qs[16][65], ks[16][65], vs[16][65];
  __shared__ float Ps[16][17];
  int idx = blockIdx.x;
  int h = idx & 7, l = (idx >> 3) & 255, b = idx >> 11;
  int lane = threadIdx.x;

  {  // vectorized loads: 6x short8 per thread (16B each)
    int tr = lane >> 2, c0 = (lane & 3) * 16;
    const __hip_bfloat16* base =
        QKVb + ((size_t)(b * kT + tr) * kL + l) * 1536 + h * 64;
    short8 qa = *(const short8*)(base + c0);
    short8 qb = *(const short8*)(base + c0 + 8);
    short8 ka = *(const short8*)(base + 512 + c0);
    short8 kb = *(const short8*)(base + 512 + c0 + 8);
    short8 va = *(const short8*)(base + 1024 + c0);
    short8 vb = *(const short8*)(base + 1024 + c0 + 8);
    #pragma unroll
    for (int j = 0; j < 8; j++) {
      qs[tr][c0 + j] = s2f(qa[j]) * kSCALE;
      qs[tr][c0 + 8 + j] = s2f(qb[j]) * kSCALE;
      ks[tr][c0 + j] = s2f(ka[j]);
      ks[tr][c0 + 8 + j] = s2f(kb[j]);
      vs[tr][c0 + j] = s2f(va[j]);
      vs[tr][c0 + 8 + j] = s2f(vb[j]);
    }
  }
  __syncthreads();
  {
    int rt = lane >> 2, rd0 = (lane & 3) * 8;
    float nq[8], nk[8];
    for (int j = 0; j < 8; j++) {
      int d = rd0 + j;
      float ang = rope[rt * kROT + d];
      float cv = cosf(ang), sv = sinf(ang);
      float oq = (d < 16) ? -qs[rt][d + 16] : qs[rt][d - 16];
      float ok = (d < 16) ? -ks[rt][d + 16] : ks[rt][d - 16];
      nq[j] = qs[rt][d] * cv + oq * sv;
      nk[j] = ks[rt][d] * cv + ok * sv;
    }
    __syncthreads();
    for (int j = 0; j < 8; j++) { qs[rt][rd0 + j] = nq[j]; ks[rt][rd0 + j] = nk[j]; }
  }
  __syncthreads();
  {
    int tq = lane >> 2, tk0 = (lane & 3) * 4;
    float s[4] = {0, 0, 0, 0};
    for (int d = 0; d < 64; d++) {
      float qv = qs[tq][d];
      s[0] += qv * ks[tk0 + 0][d];
      s[1] += qv * ks[tk0 + 1][d];
      s[2] += qv * ks[tk0 + 2][d];
      s[3] += qv * ks[tk0 + 3][d];
    }
    for (int jj = 0; jj < 4; jj++)
      Ps[tq][tk0 + jj] = amask[b * kT + tk0 + jj] ? s[jj] : kNEG;
  }
  __syncthreads();
  if (lane < 16) {
    float mx = -1e30f;
    for (int k = 0; k < 16; k++) mx = fmaxf(mx, Ps[lane][k]);
    float sum = 0.f;
    for (int k = 0; k < 16; k++) { float p = __expf(Ps[lane][k] - mx); Ps[lane][k] = p; sum += p; }
    float inv = 1.f / sum;
    for (int k = 0; k < 16; k++) Ps[lane][k] *= inv;
  }
  __syncthreads();
  for (int tq = 0; tq < 16; tq++) {
    float acc = 0.f;
    for (int tk = 0; tk < 16; tk++) acc += Ps[tq][tk] * vs[tk][lane];
    float qm = amask[b * kT + tq] ? 1.f : 0.f;
    Otb[((size_t)(b * kT + tq) * kL + l) * 512 + h * 64 + lane] = f2b(acc * qm);
  }
}

// ---------------- launcher ----------------
extern "C" void kernel_launch(void* const* d_in, const int* in_sizes, int n_in,
                              void* d_out, int out_size, void* d_ws, size_t ws_size,
                              hipStream_t stream) {
  const float* x       = (const float*)d_in[0];
  const float* ctx     = (const float*)d_in[1];
  const float* rope    = (const float*)d_in[2];
  const float* ca_ng   = (const float*)d_in[3];
  const float* ca_nb   = (const float*)d_in[4];
  const float* ca_cng  = (const float*)d_in[5];
  const float* ca_cnb  = (const float*)d_in[6];
  const float* ca_wq   = (const float*)d_in[7];
  const float* ca_wkv  = (const float*)d_in[8];
  const float* ca_wo   = (const float*)d_in[9];
  const float* ta_ng   = (const float*)d_in[10];
  const float* ta_nb   = (const float*)d_in[11];
  const float* ta_wqkv = (const float*)d_in[12];
  const float* ta_bqkv = (const float*)d_in[13];
  const float* ta_wo   = (const float*)d_in[14];
  const float* ff_ng   = (const float*)d_in[15];
  const float* ff_nb   = (const float*)d_in[16];
  const float* ff_w1   = (const float*)d_in[17];
  const float* ff_w2   = (const float*)d_in[18];
  const unsigned char* cmraw = (const unsigned char*)d_in[19];
  const unsigned char* amraw = (const unsigned char*)d_in[20];

  char* wsc = (char*)d_ws;
  size_t off = 0;
  auto take = [&](size_t bytes) {
    char* p = wsc + off;
    off = (off + bytes + 255) & ~(size_t)255;
    return p;
  };
  __hip_bfloat16* wqT   = (__hip_bfloat16*)take((size_t)1024 * 1024 * 2);
  __hip_bfloat16* wkvT  = (__hip_bfloat16*)take((size_t)2048 * 1024 * 2);
  __hip_bfloat16* woT   = (__hip_bfloat16*)take((size_t)1024 * 1024 * 2);
  __hip_bfloat16* wqkvT = (__hip_bfloat16*)take((size_t)1536 * 1024 * 2);
  __hip_bfloat16* tawoT = (__hip_bfloat16*)take((size_t)1024 * 512 * 2);
  __hip_bfloat16* ffw1T = (__hip_bfloat16*)take((size_t)4096 * 1024 * 2);
  __hip_bfloat16* ffw2T = (__hip_bfloat16*)take((size_t)1024 * 4096 * 2);
  __hip_bfloat16* XN  = (__hip_bfloat16*)take((size_t)8192 * 1024 * 2);
  __hip_bfloat16* CN  = (__hip_bfloat16*)take((size_t)1024 * 1024 * 2);
  __hip_bfloat16* Qb  = (__hip_bfloat16*)take((size_t)8192 * 1024 * 2);
  __hip_bfloat16* KVb = (__hip_bfloat16*)take((size_t)1024 * 2048 * 2);
  __hip_bfloat16* Ob  = (__hip_bfloat16*)take((size_t)8192 * 1024 * 2);
  float*          X1  = (float*)take((size_t)8192 * 1024 * 4);
  __hip_bfloat16* Hb  = (__hip_bfloat16*)take((size_t)8192 * 4096 * 2);
  int* cmask = (int*)take((size_t)kB * kM * 4);
  int* amask = (int*)take((size_t)kB * kT * 4);
  if (off > ws_size) return;

  __hip_bfloat16* QKVb = Hb;  // [8192][1536], dead before Hb is written
  __hip_bfloat16* OTb  = Qb;  // [8192][512], Q dead after cross_attn

  auto gemm = [&](const __hip_bfloat16* A, const __hip_bfloat16* Bt,
                  const float* bias, const float* res, int gelu, void* out,
                  int outBf16, int Md, int Nd, int Kd) {
    gemm_bf16<<<dim3(Md / 128, Nd / 128), dim3(256), 0, stream>>>(
        A, Bt, bias, res, gelu, out, outBf16, Md, Nd, Kd);
  };

  mask_convert<<<dim3((kB * kM + 255) / 256), dim3(256), 0, stream>>>(cmraw, kB * kM, cmask);
  mask_convert<<<dim3(1), dim3(256), 0, stream>>>(amraw, kB * kT, amask);
  transpose_w<<<dim3(1024 / 32, 1024 / 32), dim3(256), 0, stream>>>(ca_wq, wqT, 1024, 1024);
  transpose_w<<<dim3(2048 / 32, 1024 / 32), dim3(256), 0, stream>>>(ca_wkv, wkvT, 1024, 2048);
  transpose_w<<<dim3(1024 / 32, 1024 / 32), dim3(256), 0, stream>>>(ca_wo, woT, 1024, 1024);
  transpose_w<<<dim3(1536 / 32, 1024 / 32), dim3(256), 0, stream>>>(ta_wqkv, wqkvT, 1024, 1536);
  transpose_w<<<dim3(1024 / 32, 512 / 32), dim3(256), 0, stream>>>(ta_wo, tawoT, 512, 1024);
  transpose_w<<<dim3(4096 / 32, 1024 / 32), dim3(256), 0, stream>>>(ff_w1, ffw1T, 1024, 4096);
  transpose_w<<<dim3(1024 / 32, 4096 / 32), dim3(256), 0, stream>>>(ff_w2, ffw2T, 4096, 1024);

  // cross-attention block
  ln_rows<<<dim3(8192), dim3(256), 0, stream>>>(x, ca_ng, ca_nb, XN);
  ln_rows<<<dim3(1024), dim3(256), 0, stream>>>(ctx, ca_cng, ca_cnb, CN);
  gemm(XN, wqT, nullptr, nullptr, 0, Qb, 1, 8192, 1024, 1024);
  gemm(CN, wkvT, nullptr, nullptr, 0, KVb, 1, 1024, 2048, 1024);
  cross_attn_mfma<<<dim3(kN / 64, kB * kH), dim3(256), 0, stream>>>(Qb, KVb, cmask, Ob);
  gemm(Ob, woT, nullptr, x, 0, X1, 0, 8192, 1024, 1024);

  // temporal attention block
  ln_rows<<<dim3(8192), dim3(256), 0, stream>>>(X1, ta_ng, ta_nb, XN);
  gemm(XN, wqkvT, ta_bqkv, nullptr, 0, QKVb, 1, 8192, 1536, 1024);
  temporal_attn<<<dim3(kB * kL * kHT), dim3(64), 0, stream>>>(QKVb, rope, amask, OTb);
  gemm(OTb, tawoT, nullptr, X1, 0, X1, 0, 8192, 1024, 512);

  // feed-forward block
  ln_rows<<<dim3(8192), dim3(256), 0, stream>>>(X1, ff_ng, ff_nb, XN);
  gemm(XN, ffw1T, nullptr, nullptr, 1, Hb, 1, 8192, 4096, 1024);
  gemm(Hb, ffw2T, nullptr, X1, 0, d_out, 0, 8192, 1024, 4096);
}

// Round 6
// 685.659 us; speedup vs baseline: 2.2812x; 1.0324x over previous
//
#include <hip/hip_runtime.h>
#include <hip/hip_bf16.h>
#include <stdint.h>

#define DEV static __device__ __forceinline__

// Problem constants
constexpr int kB = 2, kT = 16, kL = 256, kM = 512;
constexpr int kD = 1024, kH = 16, kDH = 64, kHT = 8, kROT = 32;
constexpr int kN = kT * kL;  // 4096 flattened seq for cross-attn
constexpr float kEPS = 1e-5f;
constexpr float kNEG = -1.0e9f;
constexpr float kSCALE = 0.125f;  // 1/sqrt(64)

typedef __attribute__((ext_vector_type(8))) short short8;   // 8 bf16 (guide §3)
typedef __attribute__((ext_vector_type(4))) float floatx4;

DEV float b2f(__hip_bfloat16 v) { return __bfloat162float(v); }
DEV __hip_bfloat16 f2b(float v) { return __float2bfloat16(v); }
DEV float s2f(short x) {
  __hip_bfloat16_raw r; r.x = (unsigned short)x;
  return __bfloat162float(__hip_bfloat16(r));
}

// async global->LDS, 16B per lane; LDS dst = wave-uniform base + lane*16
DEV void gl2lds16(const __hip_bfloat16* g, __hip_bfloat16* l) {
  __builtin_amdgcn_global_load_lds(
      (const __attribute__((address_space(1))) void*)g,
      (__attribute__((address_space(3))) void*)l, 16, 0, 0);
}

// ---------------- fused transposes + mask conversion ----------------
// One launch: 7 weight transposes (fp32 [K][N] -> bf16 [N][K]) + 2 masks.
struct TransArgs {
  const float* src[7];
  __hip_bfloat16* dst[7];
  const unsigned char* cmraw;
  const unsigned char* amraw;
  int* cmask;
  int* amask;
};
// seg:            wq    wkv   wo    wqkv  tawo  ffw1  ffw2
// Kd:            1024  1024  1024  1024   512  1024  4096
// Nd:            1024  2048  1024  1536  1024  4096  1024
__constant__ const int kTKd[7] = {1024, 1024, 1024, 1024, 512, 1024, 4096};
__constant__ const int kTNd[7] = {1024, 2048, 1024, 1536, 1024, 4096, 1024};
// tiles = (Kd/32)*(Nd/32): 1024,2048,1024,1536,512,4096,4096 ; cum below
__constant__ const int kTCum[8] = {0, 1024, 3072, 4096, 5632, 6144, 10240, 14336};

DEV int mask_val(const unsigned char* raw, int i) {
  unsigned char b1 = raw[1], b3 = raw[3];
  if (b1 == 0x3F) return ((const unsigned short*)raw)[i] != 0;       // bf16
  if (b3 == 0x3F) return ((const float*)raw)[i] != 0.0f;             // fp32
  if (b1 == 1)    return raw[i] != 0;                                // bool
  return ((const int*)raw)[i] != 0;                                  // int32
}

__global__ __launch_bounds__(256) void transpose_all(TransArgs a) {
  int id = blockIdx.x;
  if (id >= 14336) {  // mask blocks
    if (id == 14336) {
      for (int i = threadIdx.x; i < kB * kM; i += 256)
        a.cmask[i] = mask_val(a.cmraw, i);
    } else {
      if (threadIdx.x < kB * kT)
        a.amask[threadIdx.x] = mask_val(a.amraw, threadIdx.x);
    }
    return;
  }
  int seg = 0;
  #pragma unroll
  for (int s = 1; s < 7; s++) seg += (id >= kTCum[s]);
  unsigned t = id - kTCum[seg];
  int Kd = kTKd[seg], Nd = kTNd[seg];
  unsigned ntx = Nd / 32;
  int n0 = (t % ntx) * 32, k0 = (t / ntx) * 32;
  const float* W = a.src[seg];
  __hip_bfloat16* Wt = a.dst[seg];
  __shared__ float tile[32][33];
  int tx = threadIdx.x & 31, ty = threadIdx.x >> 5;
  for (int i = 0; i < 32; i += 8)
    tile[ty + i][tx] = W[(size_t)(k0 + ty + i) * Nd + n0 + tx];
  __syncthreads();
  for (int i = 0; i < 32; i += 8)
    Wt[(size_t)(n0 + ty + i) * Kd + k0 + tx] = f2b(tile[tx][ty + i]);
}

// ---------------- LayerNorm over D=1024 fp32 in, bf16 out; 1 block/row -----
DEV void ln_body(const float* xr, const float* g, const float* bb,
                 __hip_bfloat16* outr, int tid) {
  float4 xv = *(const float4*)(xr + tid * 4);
  float s = xv.x + xv.y + xv.z + xv.w;
  float s2 = xv.x * xv.x + xv.y * xv.y + xv.z * xv.z + xv.w * xv.w;
  for (int off = 32; off; off >>= 1) {
    s += __shfl_down(s, off);
    s2 += __shfl_down(s2, off);
  }
  __shared__ float rs[4], rs2[4];
  if ((tid & 63) == 0) { rs[tid >> 6] = s; rs2[tid >> 6] = s2; }
  __syncthreads();
  float ts = rs[0] + rs[1] + rs[2] + rs[3];
  float ts2 = rs2[0] + rs2[1] + rs2[2] + rs2[3];
  float mu = ts * (1.f / kD);
  float var = ts2 * (1.f / kD) - mu * mu;
  float rstd = rsqrtf(var + kEPS);
  float4 gv = *(const float4*)(g + tid * 4);
  float4 bv = *(const float4*)(bb + tid * 4);
  ushort4 o;
  o.x = __hip_bfloat16_raw(f2b((xv.x - mu) * rstd * gv.x + bv.x)).x;
  o.y = __hip_bfloat16_raw(f2b((xv.y - mu) * rstd * gv.y + bv.y)).x;
  o.z = __hip_bfloat16_raw(f2b((xv.z - mu) * rstd * gv.z + bv.z)).x;
  o.w = __hip_bfloat16_raw(f2b((xv.w - mu) * rstd * gv.w + bv.w)).x;
  *(ushort4*)(outr + tid * 4) = o;
}

__global__ __launch_bounds__(256) void ln_rows(
    const float* __restrict__ X, const float* __restrict__ g,
    const float* __restrict__ bb, __hip_bfloat16* __restrict__ out) {
  int row = blockIdx.x;
  ln_body(X + (size_t)row * kD, g, bb, out + (size_t)row * kD, threadIdx.x);
}

// fused LN over x (8192 rows) and ctx (1024 rows)
__global__ __launch_bounds__(256) void ln_rows2(
    const float* __restrict__ X, const float* __restrict__ g,
    const float* __restrict__ bb, __hip_bfloat16* __restrict__ out,
    const float* __restrict__ X2, const float* __restrict__ g2,
    const float* __restrict__ bb2, __hip_bfloat16* __restrict__ out2) {
  int row = blockIdx.x;
  if (row < 8192)
    ln_body(X + (size_t)row * kD, g, bb, out + (size_t)row * kD, threadIdx.x);
  else {
    int r = row - 8192;
    ln_body(X2 + (size_t)r * kD, g2, bb2, out2 + (size_t)r * kD, threadIdx.x);
  }
}

// ---------------- MFMA GEMM core, m97 structure + BK=64 + XOR swizzle ------
// 128x128 block tile, BK=64, 4 waves in 2x2 (each 64x64 = 4x4 frags of
// 16x16x32), 2 inner halves per K-tile -> half the barrier crossings of BK=32.
// LDS layout [128 rows][8 chunks of 8 bf16]; physical chunk = logical ^ (row&7)
// (swizzle applied via per-lane SOURCE address at staging; ds_read of a fixed
// logical chunk across 16 rows then spans all 32 banks at 2 lanes/bank = free).
DEV void gemm_body(__hip_bfloat16* As, __hip_bfloat16* Bs,
                   const __hip_bfloat16* A, const __hip_bfloat16* Bt,
                   const float* bias, const float* res, int gelu,
                   void* out, int outBf16, int Nd, int Kd, int m0, int n0) {
  int tid = threadIdx.x, wave = tid >> 6, lane = tid & 63;
  int l16 = lane & 15, quad = lane >> 4;
  int wm = (wave >> 1) * 64, wn = (wave & 1) * 64;

  // staging: wave w covers rows w*32..w*32+31 (4 instrs x 8 rows), lane l ->
  // row +(l>>3), physical chunk l&7 which must hold logical (l&7)^((l>>3)&7).
  int srow = wave * 32 + (lane >> 3);
  int schunk8 = (((lane & 7) ^ ((lane >> 3) & 7)) << 3);
  const __hip_bfloat16* Ag = A + (size_t)(m0 + srow) * Kd + schunk8;
  const __hip_bfloat16* Bg = Bt + (size_t)(n0 + srow) * Kd + schunk8;
  __hip_bfloat16* Al = As + wave * 32 * 64;
  __hip_bfloat16* Bl = Bs + wave * 32 * 64;

  floatx4 acc[4][4] = {};
  for (int k0 = 0; k0 < Kd; k0 += 64) {
    #pragma unroll
    for (int i = 0; i < 4; i++) {
      gl2lds16(Ag + (size_t)(i * 8) * Kd + k0, Al + i * 512);
      gl2lds16(Bg + (size_t)(i * 8) * Kd + k0, Bl + i * 512);
    }
    __syncthreads();
    #pragma unroll
    for (int half = 0; half < 2; half++) {
      short8 af[4], bf4[4];
      #pragma unroll
      for (int mf = 0; mf < 4; mf++) {
        int row = wm + mf * 16 + l16;
        int phys = (quad + half * 4) ^ (row & 7);
        af[mf] = *(const short8*)(&As[row * 64 + phys * 8]);
      }
      #pragma unroll
      for (int nf = 0; nf < 4; nf++) {
        int row = wn + nf * 16 + l16;
        int phys = (quad + half * 4) ^ (row & 7);
        bf4[nf] = *(const short8*)(&Bs[row * 64 + phys * 8]);
      }
      #pragma unroll
      for (int mf = 0; mf < 4; mf++)
        #pragma unroll
        for (int nf = 0; nf < 4; nf++)
          acc[mf][nf] = __builtin_amdgcn_mfma_f32_16x16x32_bf16(
              af[mf], bf4[nf], acc[mf][nf], 0, 0, 0);
    }
    __syncthreads();
  }
  // epilogue: D-layout reg r -> row=quad*4+r, col=l16
  #pragma unroll
  for (int mf = 0; mf < 4; mf++) {
    #pragma unroll
    for (int nf = 0; nf < 4; nf++) {
      int col = n0 + wn + nf * 16 + l16;
      float bv = bias ? bias[col] : 0.f;
      #pragma unroll
      for (int r = 0; r < 4; r++) {
        int row = m0 + wm + mf * 16 + quad * 4 + r;
        float v = acc[mf][nf][r] + bv;
        if (gelu) {  // tanh-form GELU via sigmoid: x*sigma(1.5958x+0.07135x^3)
          float z = v * (1.5957691216f + 0.0713548162f * v * v);
          v = v * (1.f / (1.f + __expf(-z)));
        }
        size_t o = (size_t)row * Nd + col;
        if (res) v += res[o];
        if (outBf16) ((__hip_bfloat16*)out)[o] = f2b(v);
        else         ((float*)out)[o] = v;
      }
    }
  }
}

__global__ __launch_bounds__(256) void gemm_bf16(
    const __hip_bfloat16* __restrict__ A, const __hip_bfloat16* __restrict__ Bt,
    const float* __restrict__ bias, const float* __restrict__ res, int gelu,
    void* __restrict__ out, int outBf16, int Nd, int Kd) {
  __shared__ __align__(16) __hip_bfloat16 As[128 * 64];  // 16 KB
  __shared__ __align__(16) __hip_bfloat16 Bs[128 * 64];  // 16 KB
  gemm_body(As, Bs, A, Bt, bias, res, gelu, out, outBf16, Nd, Kd,
            blockIdx.x * 128, blockIdx.y * 128);
}

// grouped q-proj (512 blocks: 64x8) + kv-proj (128 blocks: 8x16), 1-D grid 640
__global__ __launch_bounds__(256) void gemm_pair(
    const __hip_bfloat16* __restrict__ A0, const __hip_bfloat16* __restrict__ B0,
    void* __restrict__ o0,
    const __hip_bfloat16* __restrict__ A1, const __hip_bfloat16* __restrict__ B1,
    void* __restrict__ o1) {
  __shared__ __align__(16) __hip_bfloat16 As[128 * 64];
  __shared__ __align__(16) __hip_bfloat16 Bs[128 * 64];
  int id = blockIdx.x;
  if (id < 512) {  // q: M=8192 N=1024 K=1024
    gemm_body(As, Bs, A0, B0, nullptr, nullptr, 0, o0, 1, 1024, 1024,
              (id & 63) * 128, (id >> 6) * 128);
  } else {         // kv: M=1024 N=2048 K=1024
    int r = id - 512;
    gemm_body(As, Bs, A1, B1, nullptr, nullptr, 0, o1, 1, 2048, 1024,
              (r & 7) * 128, (r >> 3) * 128);
  }
}

// ---------------- MFMA cross-attention (flash-style online softmax) --------
__global__ __launch_bounds__(256) void cross_attn_mfma(
    const __hip_bfloat16* __restrict__ Qb,   // [B*N][1024]
    const __hip_bfloat16* __restrict__ KVb,  // [B*M][2048] (k | v)
    const int* __restrict__ cmask,           // [B*M]
    __hip_bfloat16* __restrict__ Ob) {       // [B*N][1024]
  __shared__ __align__(16) __hip_bfloat16 Vbf[2][8][64][8];   // 16 KB
  __shared__ __align__(16) __hip_bfloat16 Paf[4][8][16][8];   // 8 KB
  int b = blockIdx.y >> 4, h = blockIdx.y & 15;
  int q0 = blockIdx.x * 64;
  int tid = threadIdx.x, wave = tid >> 6, lane = tid & 63;
  int l16 = lane & 15, quad = lane >> 4;

  const __hip_bfloat16* qrow =
      Qb + (size_t)(b * kN + q0 + wave * 16 + l16) * 1024 + h * 64 + quad * 8;
  short8 qf0 = *(const short8*)qrow;
  short8 qf1 = *(const short8*)(qrow + 32);

  floatx4 of[4] = {};
  float Mr[4] = {-1e30f, -1e30f, -1e30f, -1e30f};
  float Lr[4] = {};

  int skey = tid >> 2, sd0 = (tid & 3) * 16;

  for (int kt = 0; kt < 8; kt++) {
    int buf = kt & 1;
    {
      const __hip_bfloat16* src =
          KVb + (size_t)(b * kM + kt * 64 + skey) * 2048 + 1024 + h * 64 + sd0;
      short8 v0 = *(const short8*)src;
      short8 v1 = *(const short8*)(src + 8);
      int kb = skey >> 3, kj = skey & 7;
      #pragma unroll
      for (int j = 0; j < 8; j++) {
        Vbf[buf][kb][sd0 + j][kj] = __hip_bfloat16(__hip_bfloat16_raw{(unsigned short)v0[j]});
        Vbf[buf][kb][sd0 + 8 + j][kj] = __hip_bfloat16(__hip_bfloat16_raw{(unsigned short)v1[j]});
      }
    }
    __syncthreads();

    floatx4 sf[4];
    #pragma unroll
    for (int nf = 0; nf < 4; nf++) {
      const __hip_bfloat16* krow =
          KVb + (size_t)(b * kM + kt * 64 + nf * 16 + l16) * 2048 + h * 64 + quad * 8;
      short8 kf0 = *(const short8*)krow;
      short8 kf1 = *(const short8*)(krow + 32);
      floatx4 z = {};
      z = __builtin_amdgcn_mfma_f32_16x16x32_bf16(qf0, kf0, z, 0, 0, 0);
      z = __builtin_amdgcn_mfma_f32_16x16x32_bf16(qf1, kf1, z, 0, 0, 0);
      sf[nf] = z;
    }

    float sv[4][4];
    #pragma unroll
    for (int nf = 0; nf < 4; nf++) {
      int mk = cmask[b * kM + kt * 64 + nf * 16 + l16];
      #pragma unroll
      for (int r = 0; r < 4; r++)
        sv[nf][r] = mk ? sf[nf][r] * kSCALE : kNEG;
    }
    float mx[4];
    #pragma unroll
    for (int r = 0; r < 4; r++) {
      float m = fmaxf(fmaxf(sv[0][r], sv[1][r]), fmaxf(sv[2][r], sv[3][r]));
      #pragma unroll
      for (int off = 1; off < 16; off <<= 1) m = fmaxf(m, __shfl_xor(m, off));
      mx[r] = m;
    }
    float alpha[4], Mn[4];
    #pragma unroll
    for (int r = 0; r < 4; r++) {
      Mn[r] = fmaxf(Mr[r], mx[r]);
      alpha[r] = __expf(Mr[r] - Mn[r]);
      Mr[r] = Mn[r];
    }
    float p[4][4];
    float rsum[4];
    #pragma unroll
    for (int r = 0; r < 4; r++) {
      float s = 0.f;
      #pragma unroll
      for (int nf = 0; nf < 4; nf++) {
        float e = __expf(sv[nf][r] - Mn[r]);
        p[nf][r] = e; s += e;
      }
      #pragma unroll
      for (int off = 1; off < 16; off <<= 1) s += __shfl_xor(s, off);
      rsum[r] = s;
    }
    #pragma unroll
    for (int r = 0; r < 4; r++) Lr[r] = Lr[r] * alpha[r] + rsum[r];
    #pragma unroll
    for (int df = 0; df < 4; df++)
      #pragma unroll
      for (int r = 0; r < 4; r++) of[df][r] *= alpha[r];

    #pragma unroll
    for (int nf = 0; nf < 4; nf++) {
      int col = nf * 16 + l16;
      int kb = col >> 3, kj = col & 7;
      #pragma unroll
      for (int r = 0; r < 4; r++)
        Paf[wave][kb][quad * 4 + r][kj] = f2b(p[nf][r]);
    }
    __builtin_amdgcn_s_waitcnt(0);

    short8 pf0 = *(const short8*)(&Paf[wave][quad][l16][0]);
    short8 pf1 = *(const short8*)(&Paf[wave][quad + 4][l16][0]);
    #pragma unroll
    for (int df = 0; df < 4; df++) {
      short8 vf0 = *(const short8*)(&Vbf[buf][quad][df * 16 + l16][0]);
      short8 vf1 = *(const short8*)(&Vbf[buf][quad + 4][df * 16 + l16][0]);
      of[df] = __builtin_amdgcn_mfma_f32_16x16x32_bf16(pf0, vf0, of[df], 0, 0, 0);
      of[df] = __builtin_amdgcn_mfma_f32_16x16x32_bf16(pf1, vf1, of[df], 0, 0, 0);
    }
  }

  #pragma unroll
  for (int df = 0; df < 4; df++) {
    #pragma unroll
    for (int r = 0; r < 4; r++) {
      int row = q0 + wave * 16 + quad * 4 + r;
      float v = of[df][r] / Lr[r];
      Ob[(size_t)(b * kN + row) * 1024 + h * 64 + df * 16 + l16] = f2b(v);
    }
  }
}

// ---------------- temporal attention (with RoPE) ----------------
__global__ __launch_bounds__(64) void temporal_attn(
    const __hip_bfloat16* __restrict__ QKVb,  // [B*T*L][1536] (q|k|v)
    const float* __restrict__ rope,           // [T][32] fp32
    const int* __restrict__ amask,            // [B*T]
    __hip_bfloat16* __restrict__ Otb) {       // [B*T*L][512]
  __shared__ float qs[16][65], ks[16][65], vs[16][65];
  __shared__ float Ps[16][17];
  int idx = blockIdx.x;
  int h = idx & 7, l = (idx >> 3) & 255, b = idx >> 11;
  int lane = threadIdx.x;

  {  // vectorized loads: 6x short8 per thread (16B each)
    int tr = lane >> 2, c0 = (lane & 3) * 16;
    const __hip_bfloat16* base =
        QKVb + ((size_t)(b * kT + tr) * kL + l) * 1536 + h * 64;
    short8 qa = *(const short8*)(base + c0);
    short8 qb = *(const short8*)(base + c0 + 8);
    short8 ka = *(const short8*)(base + 512 + c0);
    short8 kb = *(const short8*)(base + 512 + c0 + 8);
    short8 va = *(const short8*)(base + 1024 + c0);
    short8 vb = *(const short8*)(base + 1024 + c0 + 8);
    #pragma unroll
    for (int j = 0; j < 8; j++) {
      qs[tr][c0 + j] = s2f(qa[j]) * kSCALE;
      qs[tr][c0 + 8 + j] = s2f(qb[j]) * kSCALE;
      ks[tr][c0 + j] = s2f(ka[j]);
      ks[tr][c0 + 8 + j] = s2f(kb[j]);
      vs[tr][c0 + j] = s2f(va[j]);
      vs[tr][c0 + 8 + j] = s2f(vb[j]);
    }
  }
  __syncthreads();
  {
    int rt = lane >> 2, rd0 = (lane & 3) * 8;
    float nq[8], nk[8];
    for (int j = 0; j < 8; j++) {
      int d = rd0 + j;
      float ang = rope[rt * kROT + d];
      float cv = cosf(ang), sv = sinf(ang);
      float oq = (d < 16) ? -qs[rt][d + 16] : qs[rt][d - 16];
      float ok = (d < 16) ? -ks[rt][d + 16] : ks[rt][d - 16];
      nq[j] = qs[rt][d] * cv + oq * sv;
      nk[j] = ks[rt][d] * cv + ok * sv;
    }
    __syncthreads();
    for (int j = 0; j < 8; j++) { qs[rt][rd0 + j] = nq[j]; ks[rt][rd0 + j] = nk[j]; }
  }
  __syncthreads();
  {
    int tq = lane >> 2, tk0 = (lane & 3) * 4;
    float s[4] = {0, 0, 0, 0};
    for (int d = 0; d < 64; d++) {
      float qv = qs[tq][d];
      s[0] += qv * ks[tk0 + 0][d];
      s[1] += qv * ks[tk0 + 1][d];
      s[2] += qv * ks[tk0 + 2][d];
      s[3] += qv * ks[tk0 + 3][d];
    }
    for (int jj = 0; jj < 4; jj++)
      Ps[tq][tk0 + jj] = amask[b * kT + tk0 + jj] ? s[jj] : kNEG;
  }
  __syncthreads();
  if (lane < 16) {
    float mx = -1e30f;
    for (int k = 0; k < 16; k++) mx = fmaxf(mx, Ps[lane][k]);
    float sum = 0.f;
    for (int k = 0; k < 16; k++) { float p = __expf(Ps[lane][k] - mx); Ps[lane][k] = p; sum += p; }
    float inv = 1.f / sum;
    for (int k = 0; k < 16; k++) Ps[lane][k] *= inv;
  }
  __syncthreads();
  for (int tq = 0; tq < 16; tq++) {
    float acc = 0.f;
    for (int tk = 0; tk < 16; tk++) acc += Ps[tq][tk] * vs[tk][lane];
    float qm = amask[b * kT + tq] ? 1.f : 0.f;
    Otb[((size_t)(b * kT + tq) * kL + l) * 512 + h * 64 + lane] = f2b(acc * qm);
  }
}

// ---------------- launcher ----------------
extern "C" void kernel_launch(void* const* d_in, const int* in_sizes, int n_in,
                              void* d_out, int out_size, void* d_ws, size_t ws_size,
                              hipStream_t stream) {
  const float* x       = (const float*)d_in[0];
  const float* ctx     = (const float*)d_in[1];
  const float* rope    = (const float*)d_in[2];
  const float* ca_ng   = (const float*)d_in[3];
  const float* ca_nb   = (const float*)d_in[4];
  const float* ca_cng  = (const float*)d_in[5];
  const float* ca_cnb  = (const float*)d_in[6];
  const float* ca_wq   = (const float*)d_in[7];
  const float* ca_wkv  = (const float*)d_in[8];
  const float* ca_wo   = (const float*)d_in[9];
  const float* ta_ng   = (const float*)d_in[10];
  const float* ta_nb   = (const float*)d_in[11];
  const float* ta_wqkv = (const float*)d_in[12];
  const float* ta_bqkv = (const float*)d_in[13];
  const float* ta_wo   = (const float*)d_in[14];
  const float* ff_ng   = (const float*)d_in[15];
  const float* ff_nb   = (const float*)d_in[16];
  const float* ff_w1   = (const float*)d_in[17];
  const float* ff_w2   = (const float*)d_in[18];
  const unsigned char* cmraw = (const unsigned char*)d_in[19];
  const unsigned char* amraw = (const unsigned char*)d_in[20];

  char* wsc = (char*)d_ws;
  size_t off = 0;
  auto take = [&](size_t bytes) {
    char* p = wsc + off;
    off = (off + bytes + 255) & ~(size_t)255;
    return p;
  };
  __hip_bfloat16* wqT   = (__hip_bfloat16*)take((size_t)1024 * 1024 * 2);
  __hip_bfloat16* wkvT  = (__hip_bfloat16*)take((size_t)2048 * 1024 * 2);
  __hip_bfloat16* woT   = (__hip_bfloat16*)take((size_t)1024 * 1024 * 2);
  __hip_bfloat16* wqkvT = (__hip_bfloat16*)take((size_t)1536 * 1024 * 2);
  __hip_bfloat16* tawoT = (__hip_bfloat16*)take((size_t)1024 * 512 * 2);
  __hip_bfloat16* ffw1T = (__hip_bfloat16*)take((size_t)4096 * 1024 * 2);
  __hip_bfloat16* ffw2T = (__hip_bfloat16*)take((size_t)1024 * 4096 * 2);
  __hip_bfloat16* XN  = (__hip_bfloat16*)take((size_t)8192 * 1024 * 2);
  __hip_bfloat16* CN  = (__hip_bfloat16*)take((size_t)1024 * 1024 * 2);
  __hip_bfloat16* Qb  = (__hip_bfloat16*)take((size_t)8192 * 1024 * 2);
  __hip_bfloat16* KVb = (__hip_bfloat16*)take((size_t)1024 * 2048 * 2);
  __hip_bfloat16* Ob  = (__hip_bfloat16*)take((size_t)8192 * 1024 * 2);
  float*          X1  = (float*)take((size_t)8192 * 1024 * 4);
  __hip_bfloat16* Hb  = (__hip_bfloat16*)take((size_t)8192 * 4096 * 2);
  int* cmask = (int*)take((size_t)kB * kM * 4);
  int* amask = (int*)take((size_t)kB * kT * 4);
  if (off > ws_size) return;

  __hip_bfloat16* QKVb = Hb;  // [8192][1536], dead before Hb is written
  __hip_bfloat16* OTb  = Qb;  // [8192][512], Q dead after cross_attn

  auto gemm = [&](const __hip_bfloat16* A, const __hip_bfloat16* Bt,
                  const float* bias, const float* res, int gelu, void* out,
                  int outBf16, int Md, int Nd, int Kd) {
    gemm_bf16<<<dim3(Md / 128, Nd / 128), dim3(256), 0, stream>>>(
        A, Bt, bias, res, gelu, out, outBf16, Nd, Kd);
  };

  // fused transposes + masks (1 launch)
  TransArgs ta;
  ta.src[0] = ca_wq;   ta.dst[0] = wqT;
  ta.src[1] = ca_wkv;  ta.dst[1] = wkvT;
  ta.src[2] = ca_wo;   ta.dst[2] = woT;
  ta.src[3] = ta_wqkv; ta.dst[3] = wqkvT;
  ta.src[4] = ta_wo;   ta.dst[4] = tawoT;
  ta.src[5] = ff_w1;   ta.dst[5] = ffw1T;
  ta.src[6] = ff_w2;   ta.dst[6] = ffw2T;
  ta.cmraw = cmraw; ta.amraw = amraw; ta.cmask = cmask; ta.amask = amask;
  transpose_all<<<dim3(14338), dim3(256), 0, stream>>>(ta);

  // cross-attention block
  ln_rows2<<<dim3(9216), dim3(256), 0, stream>>>(x, ca_ng, ca_nb, XN,
                                                 ctx, ca_cng, ca_cnb, CN);
  gemm_pair<<<dim3(640), dim3(256), 0, stream>>>(XN, wqT, Qb, CN, wkvT, KVb);
  cross_attn_mfma<<<dim3(kN / 64, kB * kH), dim3(256), 0, stream>>>(Qb, KVb, cmask, Ob);
  gemm(Ob, woT, nullptr, x, 0, X1, 0, 8192, 1024, 1024);

  // temporal attention block
  ln_rows<<<dim3(8192), dim3(256), 0, stream>>>(X1, ta_ng, ta_nb, XN);
  gemm(XN, wqkvT, ta_bqkv, nullptr, 0, QKVb, 1, 8192, 1536, 1024);
  temporal_attn<<<dim3(kB * kL * kHT), dim3(64), 0, stream>>>(QKVb, rope, amask, OTb);
  gemm(OTb, tawoT, nullptr, X1, 0, X1, 0, 8192, 1024, 512);

  // feed-forward block
  ln_rows<<<dim3(8192), dim3(256), 0, stream>>>(X1, ff_ng, ff_nb, XN);
  gemm(XN, ffw1T, nullptr, nullptr, 1, Hb, 1, 8192, 4096, 1024);
  gemm(Hb, ffw2T, nullptr, X1, 0, d_out, 0, 8192, 1024, 4096);
}

// Round 7
// 640.931 us; speedup vs baseline: 2.4404x; 1.0698x over previous
//
#include <hip/hip_runtime.h>
#include <hip/hip_bf16.h>
#include <stdint.h>

#define DEV static __device__ __forceinline__

// Problem constants
constexpr int kB = 2, kT = 16, kL = 256, kM = 512;
constexpr int kD = 1024, kH = 16, kDH = 64, kHT = 8, kROT = 32;
constexpr int kN = kT * kL;  // 4096 flattened seq for cross-attn
constexpr float kEPS = 1e-5f;
constexpr float kNEG = -1.0e9f;
constexpr float kSCALE = 0.125f;  // 1/sqrt(64)

typedef __attribute__((ext_vector_type(8))) short short8;   // 8 bf16 (guide §3)
typedef __attribute__((ext_vector_type(4))) float floatx4;
typedef __attribute__((ext_vector_type(16))) float floatx16;

DEV float b2f(__hip_bfloat16 v) { return __bfloat162float(v); }
DEV __hip_bfloat16 f2b(float v) { return __float2bfloat16(v); }
DEV float s2f(short x) {
  __hip_bfloat16_raw r; r.x = (unsigned short)x;
  return __bfloat162float(__hip_bfloat16(r));
}

// async global->LDS, 16B per lane; LDS dst = wave-uniform base + lane*16
DEV void gl2lds16(const __hip_bfloat16* g, __hip_bfloat16* l) {
  __builtin_amdgcn_global_load_lds(
      (const __attribute__((address_space(1))) void*)g,
      (__attribute__((address_space(3))) void*)l, 16, 0, 0);
}

// ---------------- fused transposes + mask conversion ----------------
struct TransArgs {
  const float* src[7];
  __hip_bfloat16* dst[7];
  const unsigned char* cmraw;
  const unsigned char* amraw;
  int* cmask;
  int* amask;
};
__constant__ const int kTKd[7] = {1024, 1024, 1024, 1024, 512, 1024, 4096};
__constant__ const int kTNd[7] = {1024, 2048, 1024, 1536, 1024, 4096, 1024};
__constant__ const int kTCum[8] = {0, 1024, 3072, 4096, 5632, 6144, 10240, 14336};

DEV int mask_val(const unsigned char* raw, int i) {
  unsigned char b1 = raw[1], b3 = raw[3];
  if (b1 == 0x3F) return ((const unsigned short*)raw)[i] != 0;       // bf16
  if (b3 == 0x3F) return ((const float*)raw)[i] != 0.0f;             // fp32
  if (b1 == 1)    return raw[i] != 0;                                // bool
  return ((const int*)raw)[i] != 0;                                  // int32
}

__global__ __launch_bounds__(256) void transpose_all(TransArgs a) {
  int id = blockIdx.x;
  if (id >= 14336) {  // mask blocks
    if (id == 14336) {
      for (int i = threadIdx.x; i < kB * kM; i += 256)
        a.cmask[i] = mask_val(a.cmraw, i);
    } else {
      if (threadIdx.x < kB * kT)
        a.amask[threadIdx.x] = mask_val(a.amraw, threadIdx.x);
    }
    return;
  }
  int seg = 0;
  #pragma unroll
  for (int s = 1; s < 7; s++) seg += (id >= kTCum[s]);
  unsigned t = id - kTCum[seg];
  int Kd = kTKd[seg], Nd = kTNd[seg];
  unsigned ntx = Nd / 32;
  int n0 = (t % ntx) * 32, k0 = (t / ntx) * 32;
  const float* W = a.src[seg];
  __hip_bfloat16* Wt = a.dst[seg];
  __shared__ float tile[32][33];
  int tx = threadIdx.x & 31, ty = threadIdx.x >> 5;
  for (int i = 0; i < 32; i += 8)
    tile[ty + i][tx] = W[(size_t)(k0 + ty + i) * Nd + n0 + tx];
  __syncthreads();
  for (int i = 0; i < 32; i += 8)
    Wt[(size_t)(n0 + ty + i) * Kd + k0 + tx] = f2b(tile[tx][ty + i]);
}

// ---------------- LayerNorm over D=1024 fp32 in, bf16 out; 1 block/row -----
DEV void ln_body(const float* xr, const float* g, const float* bb,
                 __hip_bfloat16* outr, int tid) {
  float4 xv = *(const float4*)(xr + tid * 4);
  float s = xv.x + xv.y + xv.z + xv.w;
  float s2 = xv.x * xv.x + xv.y * xv.y + xv.z * xv.z + xv.w * xv.w;
  for (int off = 32; off; off >>= 1) {
    s += __shfl_down(s, off);
    s2 += __shfl_down(s2, off);
  }
  __shared__ float rs[4], rs2[4];
  if ((tid & 63) == 0) { rs[tid >> 6] = s; rs2[tid >> 6] = s2; }
  __syncthreads();
  float ts = rs[0] + rs[1] + rs[2] + rs[3];
  float ts2 = rs2[0] + rs2[1] + rs2[2] + rs2[3];
  float mu = ts * (1.f / kD);
  float var = ts2 * (1.f / kD) - mu * mu;
  float rstd = rsqrtf(var + kEPS);
  float4 gv = *(const float4*)(g + tid * 4);
  float4 bv = *(const float4*)(bb + tid * 4);
  ushort4 o;
  o.x = __hip_bfloat16_raw(f2b((xv.x - mu) * rstd * gv.x + bv.x)).x;
  o.y = __hip_bfloat16_raw(f2b((xv.y - mu) * rstd * gv.y + bv.y)).x;
  o.z = __hip_bfloat16_raw(f2b((xv.z - mu) * rstd * gv.z + bv.z)).x;
  o.w = __hip_bfloat16_raw(f2b((xv.w - mu) * rstd * gv.w + bv.w)).x;
  *(ushort4*)(outr + tid * 4) = o;
}

__global__ __launch_bounds__(256) void ln_rows(
    const float* __restrict__ X, const float* __restrict__ g,
    const float* __restrict__ bb, __hip_bfloat16* __restrict__ out) {
  int row = blockIdx.x;
  ln_body(X + (size_t)row * kD, g, bb, out + (size_t)row * kD, threadIdx.x);
}

// fused LN over x (8192 rows) and ctx (1024 rows)
__global__ __launch_bounds__(256) void ln_rows2(
    const float* __restrict__ X, const float* __restrict__ g,
    const float* __restrict__ bb, __hip_bfloat16* __restrict__ out,
    const float* __restrict__ X2, const float* __restrict__ g2,
    const float* __restrict__ bb2, __hip_bfloat16* __restrict__ out2) {
  int row = blockIdx.x;
  if (row < 8192)
    ln_body(X + (size_t)row * kD, g, bb, out + (size_t)row * kD, threadIdx.x);
  else {
    int r = row - 8192;
    ln_body(X2 + (size_t)r * kD, g2, bb2, out2 + (size_t)r * kD, threadIdx.x);
  }
}

// ---------------- MFMA GEMM core: 128x128 tile, BK=64, 32x32x16 MFMA ------
// 4 waves in 2x2, each wave 64x64 = 2x2 frags of 32x32x16 (half the MFMA
// instruction count of 16x16x32 at better FLOP/cyc — m119: 2495 vs 2176 TF).
// LDS [128 rows][8 chunks of 16B]; physical chunk = logical ^ (row&7), swizzle
// applied via per-lane SOURCE address at staging (round-6: 0 bank conflicts).
// Frag maps (m74/m101 C/D; A/B generalize m89's verified 16x16 pattern):
//   A/B: m|n = lane&31, k = (lane>>5)*8 + j
//   C/D: reg r -> row = (r&3) + 8*(r>>2) + 4*(lane>>5), col = lane&31
DEV void gemm_body(__hip_bfloat16* As, __hip_bfloat16* Bs,
                   const __hip_bfloat16* A, const __hip_bfloat16* Bt,
                   const float* bias, const float* res, int gelu,
                   void* out, int outBf16, int Nd, int Kd, int m0, int n0) {
  int tid = threadIdx.x, wave = tid >> 6, lane = tid & 63;
  int l32 = lane & 31, kg = lane >> 5;
  int wm = (wave >> 1) * 64, wn = (wave & 1) * 64;

  // staging: wave w covers rows w*32..w*32+31 (4 instrs x 8 rows), lane l ->
  // row +(l>>3), physical chunk l&7 holding logical (l&7)^((l>>3)&7).
  int srow = wave * 32 + (lane >> 3);
  int schunk8 = (((lane & 7) ^ ((lane >> 3) & 7)) << 3);
  const __hip_bfloat16* Ag = A + (size_t)(m0 + srow) * Kd + schunk8;
  const __hip_bfloat16* Bg = Bt + (size_t)(n0 + srow) * Kd + schunk8;
  __hip_bfloat16* Al = As + wave * 32 * 64;
  __hip_bfloat16* Bl = Bs + wave * 32 * 64;

  floatx16 acc[2][2] = {};
  for (int k0 = 0; k0 < Kd; k0 += 64) {
    #pragma unroll
    for (int i = 0; i < 4; i++) {
      gl2lds16(Ag + (size_t)(i * 8) * Kd + k0, Al + i * 512);
      gl2lds16(Bg + (size_t)(i * 8) * Kd + k0, Bl + i * 512);
    }
    __syncthreads();  // compiler drains vmcnt before s_barrier
    #pragma unroll
    for (int ks = 0; ks < 4; ks++) {  // K-steps of 16
      int c = ks * 2 + kg;            // logical 16B chunk
      short8 af[2], bf2[2];
      #pragma unroll
      for (int fa = 0; fa < 2; fa++) {
        int row = wm + fa * 32 + l32;
        af[fa] = *(const short8*)(&As[row * 64 + (c ^ (row & 7)) * 8]);
      }
      #pragma unroll
      for (int fb = 0; fb < 2; fb++) {
        int row = wn + fb * 32 + l32;
        bf2[fb] = *(const short8*)(&Bs[row * 64 + (c ^ (row & 7)) * 8]);
      }
      #pragma unroll
      for (int fa = 0; fa < 2; fa++)
        #pragma unroll
        for (int fb = 0; fb < 2; fb++)
          acc[fa][fb] = __builtin_amdgcn_mfma_f32_32x32x16_bf16(
              af[fa], bf2[fb], acc[fa][fb], 0, 0, 0);
    }
    __syncthreads();
  }
  // epilogue
  #pragma unroll
  for (int fa = 0; fa < 2; fa++) {
    #pragma unroll
    for (int fb = 0; fb < 2; fb++) {
      int col = n0 + wn + fb * 32 + l32;
      float bv = bias ? bias[col] : 0.f;
      #pragma unroll
      for (int r = 0; r < 16; r++) {
        int row = m0 + wm + fa * 32 + (r & 3) + 8 * (r >> 2) + 4 * kg;
        float v = acc[fa][fb][r] + bv;
        if (gelu) {  // gelu(x) ~= x * sigmoid(1.702 x)
          v = v * (1.f / (1.f + __expf(-1.702f * v)));
        }
        size_t o = (size_t)row * Nd + col;
        if (res) v += res[o];
        if (outBf16) ((__hip_bfloat16*)out)[o] = f2b(v);
        else         ((float*)out)[o] = v;
      }
    }
  }
}

__global__ __launch_bounds__(256) void gemm_bf16(
    const __hip_bfloat16* __restrict__ A, const __hip_bfloat16* __restrict__ Bt,
    const float* __restrict__ bias, const float* __restrict__ res, int gelu,
    void* __restrict__ out, int outBf16, int Nd, int Kd) {
  __shared__ __align__(16) __hip_bfloat16 As[128 * 64];  // 16 KB
  __shared__ __align__(16) __hip_bfloat16 Bs[128 * 64];  // 16 KB
  gemm_body(As, Bs, A, Bt, bias, res, gelu, out, outBf16, Nd, Kd,
            blockIdx.x * 128, blockIdx.y * 128);
}

// grouped q-proj (512 blocks: 64x8) + kv-proj (128 blocks: 8x16), 1-D grid 640
__global__ __launch_bounds__(256) void gemm_pair(
    const __hip_bfloat16* __restrict__ A0, const __hip_bfloat16* __restrict__ B0,
    void* __restrict__ o0,
    const __hip_bfloat16* __restrict__ A1, const __hip_bfloat16* __restrict__ B1,
    void* __restrict__ o1) {
  __shared__ __align__(16) __hip_bfloat16 As[128 * 64];
  __shared__ __align__(16) __hip_bfloat16 Bs[128 * 64];
  int id = blockIdx.x;
  if (id < 512) {  // q: M=8192 N=1024 K=1024
    gemm_body(As, Bs, A0, B0, nullptr, nullptr, 0, o0, 1, 1024, 1024,
              (id & 63) * 128, (id >> 6) * 128);
  } else {         // kv: M=1024 N=2048 K=1024
    int r = id - 512;
    gemm_body(As, Bs, A1, B1, nullptr, nullptr, 0, o1, 1, 2048, 1024,
              (r & 7) * 128, (r >> 3) * 128);
  }
}

// ---------------- MFMA cross-attention (flash-style online softmax) --------
__global__ __launch_bounds__(256) void cross_attn_mfma(
    const __hip_bfloat16* __restrict__ Qb,   // [B*N][1024]
    const __hip_bfloat16* __restrict__ KVb,  // [B*M][2048] (k | v)
    const int* __restrict__ cmask,           // [B*M]
    __hip_bfloat16* __restrict__ Ob) {       // [B*N][1024]
  __shared__ __align__(16) __hip_bfloat16 Vbf[2][8][64][8];   // 16 KB
  __shared__ __align__(16) __hip_bfloat16 Paf[4][8][16][8];   // 8 KB
  int b = blockIdx.y >> 4, h = blockIdx.y & 15;
  int q0 = blockIdx.x * 64;
  int tid = threadIdx.x, wave = tid >> 6, lane = tid & 63;
  int l16 = lane & 15, quad = lane >> 4;

  const __hip_bfloat16* qrow =
      Qb + (size_t)(b * kN + q0 + wave * 16 + l16) * 1024 + h * 64 + quad * 8;
  short8 qf0 = *(const short8*)qrow;
  short8 qf1 = *(const short8*)(qrow + 32);

  floatx4 of[4] = {};
  float Mr[4] = {-1e30f, -1e30f, -1e30f, -1e30f};
  float Lr[4] = {};

  int skey = tid >> 2, sd0 = (tid & 3) * 16;

  for (int kt = 0; kt < 8; kt++) {
    int buf = kt & 1;
    {
      const __hip_bfloat16* src =
          KVb + (size_t)(b * kM + kt * 64 + skey) * 2048 + 1024 + h * 64 + sd0;
      short8 v0 = *(const short8*)src;
      short8 v1 = *(const short8*)(src + 8);
      int kb = skey >> 3, kj = skey & 7;
      #pragma unroll
      for (int j = 0; j < 8; j++) {
        Vbf[buf][kb][sd0 + j][kj] = __hip_bfloat16(__hip_bfloat16_raw{(unsigned short)v0[j]});
        Vbf[buf][kb][sd0 + 8 + j][kj] = __hip_bfloat16(__hip_bfloat16_raw{(unsigned short)v1[j]});
      }
    }
    __syncthreads();

    floatx4 sf[4];
    #pragma unroll
    for (int nf = 0; nf < 4; nf++) {
      const __hip_bfloat16* krow =
          KVb + (size_t)(b * kM + kt * 64 + nf * 16 + l16) * 2048 + h * 64 + quad * 8;
      short8 kf0 = *(const short8*)krow;
      short8 kf1 = *(const short8*)(krow + 32);
      floatx4 z = {};
      z = __builtin_amdgcn_mfma_f32_16x16x32_bf16(qf0, kf0, z, 0, 0, 0);
      z = __builtin_amdgcn_mfma_f32_16x16x32_bf16(qf1, kf1, z, 0, 0, 0);
      sf[nf] = z;
    }

    float sv[4][4];
    #pragma unroll
    for (int nf = 0; nf < 4; nf++) {
      int mk = cmask[b * kM + kt * 64 + nf * 16 + l16];
      #pragma unroll
      for (int r = 0; r < 4; r++)
        sv[nf][r] = mk ? sf[nf][r] * kSCALE : kNEG;
    }
    float mx[4];
    #pragma unroll
    for (int r = 0; r < 4; r++) {
      float m = fmaxf(fmaxf(sv[0][r], sv[1][r]), fmaxf(sv[2][r], sv[3][r]));
      #pragma unroll
      for (int off = 1; off < 16; off <<= 1) m = fmaxf(m, __shfl_xor(m, off));
      mx[r] = m;
    }
    float alpha[4], Mn[4];
    #pragma unroll
    for (int r = 0; r < 4; r++) {
      Mn[r] = fmaxf(Mr[r], mx[r]);
      alpha[r] = __expf(Mr[r] - Mn[r]);
      Mr[r] = Mn[r];
    }
    float p[4][4];
    float rsum[4];
    #pragma unroll
    for (int r = 0; r < 4; r++) {
      float s = 0.f;
      #pragma unroll
      for (int nf = 0; nf < 4; nf++) {
        float e = __expf(sv[nf][r] - Mn[r]);
        p[nf][r] = e; s += e;
      }
      #pragma unroll
      for (int off = 1; off < 16; off <<= 1) s += __shfl_xor(s, off);
      rsum[r] = s;
    }
    #pragma unroll
    for (int r = 0; r < 4; r++) Lr[r] = Lr[r] * alpha[r] + rsum[r];
    #pragma unroll
    for (int df = 0; df < 4; df++)
      #pragma unroll
      for (int r = 0; r < 4; r++) of[df][r] *= alpha[r];

    #pragma unroll
    for (int nf = 0; nf < 4; nf++) {
      int col = nf * 16 + l16;
      int kb = col >> 3, kj = col & 7;
      #pragma unroll
      for (int r = 0; r < 4; r++)
        Paf[wave][kb][quad * 4 + r][kj] = f2b(p[nf][r]);
    }
    __builtin_amdgcn_s_waitcnt(0);

    short8 pf0 = *(const short8*)(&Paf[wave][quad][l16][0]);
    short8 pf1 = *(const short8*)(&Paf[wave][quad + 4][l16][0]);
    #pragma unroll
    for (int df = 0; df < 4; df++) {
      short8 vf0 = *(const short8*)(&Vbf[buf][quad][df * 16 + l16][0]);
      short8 vf1 = *(const short8*)(&Vbf[buf][quad + 4][df * 16 + l16][0]);
      of[df] = __builtin_amdgcn_mfma_f32_16x16x32_bf16(pf0, vf0, of[df], 0, 0, 0);
      of[df] = __builtin_amdgcn_mfma_f32_16x16x32_bf16(pf1, vf1, of[df], 0, 0, 0);
    }
  }

  #pragma unroll
  for (int df = 0; df < 4; df++) {
    #pragma unroll
    for (int r = 0; r < 4; r++) {
      int row = q0 + wave * 16 + quad * 4 + r;
      float v = of[df][r] / Lr[r];
      Ob[(size_t)(b * kN + row) * 1024 + h * 64 + df * 16 + l16] = f2b(v);
    }
  }
}

// ---------------- temporal attention (with RoPE) ----------------
__global__ __launch_bounds__(64) void temporal_attn(
    const __hip_bfloat16* __restrict__ QKVb,  // [B*T*L][1536] (q|k|v)
    const float* __restrict__ rope,           // [T][32] fp32
    const int* __restrict__ amask,            // [B*T]
    __hip_bfloat16* __restrict__ Otb) {       // [B*T*L][512]
  __shared__ float qs[16][65], ks[16][65], vs[16][65];
  __shared__ float Ps[16][17];
  int idx = blockIdx.x;
  int h = idx & 7, l = (idx >> 3) & 255, b = idx >> 11;
  int lane = threadIdx.x;

  {  // vectorized loads: 6x short8 per thread (16B each)
    int tr = lane >> 2, c0 = (lane & 3) * 16;
    const __hip_bfloat16* base =
        QKVb + ((size_t)(b * kT + tr) * kL + l) * 1536 + h * 64;
    short8 qa = *(const short8*)(base + c0);
    short8 qb = *(const short8*)(base + c0 + 8);
    short8 ka = *(const short8*)(base + 512 + c0);
    short8 kb = *(const short8*)(base + 512 + c0 + 8);
    short8 va = *(const short8*)(base + 1024 + c0);
    short8 vb = *(const short8*)(base + 1024 + c0 + 8);
    #pragma unroll
    for (int j = 0; j < 8; j++) {
      qs[tr][c0 + j] = s2f(qa[j]) * kSCALE;
      qs[tr][c0 + 8 + j] = s2f(qb[j]) * kSCALE;
      ks[tr][c0 + j] = s2f(ka[j]);
      ks[tr][c0 + 8 + j] = s2f(kb[j]);
      vs[tr][c0 + j] = s2f(va[j]);
      vs[tr][c0 + 8 + j] = s2f(vb[j]);
    }
  }
  __syncthreads();
  {
    int rt = lane >> 2, rd0 = (lane & 3) * 8;
    float nq[8], nk[8];
    for (int j = 0; j < 8; j++) {
      int d = rd0 + j;
      float ang = rope[rt * kROT + d];
      float cv = cosf(ang), sv = sinf(ang);
      float oq = (d < 16) ? -qs[rt][d + 16] : qs[rt][d - 16];
      float ok = (d < 16) ? -ks[rt][d + 16] : ks[rt][d - 16];
      nq[j] = qs[rt][d] * cv + oq * sv;
      nk[j] = ks[rt][d] * cv + ok * sv;
    }
    __syncthreads();
    for (int j = 0; j < 8; j++) { qs[rt][rd0 + j] = nq[j]; ks[rt][rd0 + j] = nk[j]; }
  }
  __syncthreads();
  {
    int tq = lane >> 2, tk0 = (lane & 3) * 4;
    float s[4] = {0, 0, 0, 0};
    for (int d = 0; d < 64; d++) {
      float qv = qs[tq][d];
      s[0] += qv * ks[tk0 + 0][d];
      s[1] += qv * ks[tk0 + 1][d];
      s[2] += qv * ks[tk0 + 2][d];
      s[3] += qv * ks[tk0 + 3][d];
    }
    for (int jj = 0; jj < 4; jj++)
      Ps[tq][tk0 + jj] = amask[b * kT + tk0 + jj] ? s[jj] : kNEG;
  }
  __syncthreads();
  if (lane < 16) {
    float mx = -1e30f;
    for (int k = 0; k < 16; k++) mx = fmaxf(mx, Ps[lane][k]);
    float sum = 0.f;
    for (int k = 0; k < 16; k++) { float p = __expf(Ps[lane][k] - mx); Ps[lane][k] = p; sum += p; }
    float inv = 1.f / sum;
    for (int k = 0; k < 16; k++) Ps[lane][k] *= inv;
  }
  __syncthreads();
  for (int tq = 0; tq < 16; tq++) {
    float acc = 0.f;
    for (int tk = 0; tk < 16; tk++) acc += Ps[tq][tk] * vs[tk][lane];
    float qm = amask[b * kT + tq] ? 1.f : 0.f;
    Otb[((size_t)(b * kT + tq) * kL + l) * 512 + h * 64 + lane] = f2b(acc * qm);
  }
}

// ---------------- launcher ----------------
extern "C" void kernel_launch(void* const* d_in, const int* in_sizes, int n_in,
                              void* d_out, int out_size, void* d_ws, size_t ws_size,
                              hipStream_t stream) {
  const float* x       = (const float*)d_in[0];
  const float* ctx     = (const float*)d_in[1];
  const float* rope    = (const float*)d_in[2];
  const float* ca_ng   = (const float*)d_in[3];
  const float* ca_nb   = (const float*)d_in[4];
  const float* ca_cng  = (const float*)d_in[5];
  const float* ca_cnb  = (const float*)d_in[6];
  const float* ca_wq   = (const float*)d_in[7];
  const float* ca_wkv  = (const float*)d_in[8];
  const float* ca_wo   = (const float*)d_in[9];
  const float* ta_ng   = (const float*)d_in[10];
  const float* ta_nb   = (const float*)d_in[11];
  const float* ta_wqkv = (const float*)d_in[12];
  const float* ta_bqkv = (const float*)d_in[13];
  const float* ta_wo   = (const float*)d_in[14];
  const float* ff_ng   = (const float*)d_in[15];
  const float* ff_nb   = (const float*)d_in[16];
  const float* ff_w1   = (const float*)d_in[17];
  const float* ff_w2   = (const float*)d_in[18];
  const unsigned char* cmraw = (const unsigned char*)d_in[19];
  const unsigned char* amraw = (const unsigned char*)d_in[20];

  char* wsc = (char*)d_ws;
  size_t off = 0;
  auto take = [&](size_t bytes) {
    char* p = wsc + off;
    off = (off + bytes + 255) & ~(size_t)255;
    return p;
  };
  __hip_bfloat16* wqT   = (__hip_bfloat16*)take((size_t)1024 * 1024 * 2);
  __hip_bfloat16* wkvT  = (__hip_bfloat16*)take((size_t)2048 * 1024 * 2);
  __hip_bfloat16* woT   = (__hip_bfloat16*)take((size_t)1024 * 1024 * 2);
  __hip_bfloat16* wqkvT = (__hip_bfloat16*)take((size_t)1536 * 1024 * 2);
  __hip_bfloat16* tawoT = (__hip_bfloat16*)take((size_t)1024 * 512 * 2);
  __hip_bfloat16* ffw1T = (__hip_bfloat16*)take((size_t)4096 * 1024 * 2);
  __hip_bfloat16* ffw2T = (__hip_bfloat16*)take((size_t)1024 * 4096 * 2);
  __hip_bfloat16* XN  = (__hip_bfloat16*)take((size_t)8192 * 1024 * 2);
  __hip_bfloat16* CN  = (__hip_bfloat16*)take((size_t)1024 * 1024 * 2);
  __hip_bfloat16* Qb  = (__hip_bfloat16*)take((size_t)8192 * 1024 * 2);
  __hip_bfloat16* KVb = (__hip_bfloat16*)take((size_t)1024 * 2048 * 2);
  __hip_bfloat16* Ob  = (__hip_bfloat16*)take((size_t)8192 * 1024 * 2);
  float*          X1  = (float*)take((size_t)8192 * 1024 * 4);
  __hip_bfloat16* Hb  = (__hip_bfloat16*)take((size_t)8192 * 4096 * 2);
  int* cmask = (int*)take((size_t)kB * kM * 4);
  int* amask = (int*)take((size_t)kB * kT * 4);
  if (off > ws_size) return;

  __hip_bfloat16* QKVb = Hb;  // [8192][1536], dead before Hb is written
  __hip_bfloat16* OTb  = Qb;  // [8192][512], Q dead after cross_attn

  auto gemm = [&](const __hip_bfloat16* A, const __hip_bfloat16* Bt,
                  const float* bias, const float* res, int gelu, void* out,
                  int outBf16, int Md, int Nd, int Kd) {
    gemm_bf16<<<dim3(Md / 128, Nd / 128), dim3(256), 0, stream>>>(
        A, Bt, bias, res, gelu, out, outBf16, Nd, Kd);
  };

  // fused transposes + masks (1 launch)
  TransArgs ta;
  ta.src[0] = ca_wq;   ta.dst[0] = wqT;
  ta.src[1] = ca_wkv;  ta.dst[1] = wkvT;
  ta.src[2] = ca_wo;   ta.dst[2] = woT;
  ta.src[3] = ta_wqkv; ta.dst[3] = wqkvT;
  ta.src[4] = ta_wo;   ta.dst[4] = tawoT;
  ta.src[5] = ff_w1;   ta.dst[5] = ffw1T;
  ta.src[6] = ff_w2;   ta.dst[6] = ffw2T;
  ta.cmraw = cmraw; ta.amraw = amraw; ta.cmask = cmask; ta.amask = amask;
  transpose_all<<<dim3(14338), dim3(256), 0, stream>>>(ta);

  // cross-attention block
  ln_rows2<<<dim3(9216), dim3(256), 0, stream>>>(x, ca_ng, ca_nb, XN,
                                                 ctx, ca_cng, ca_cnb, CN);
  gemm_pair<<<dim3(640), dim3(256), 0, stream>>>(XN, wqT, Qb, CN, wkvT, KVb);
  cross_attn_mfma<<<dim3(kN / 64, kB * kH), dim3(256), 0, stream>>>(Qb, KVb, cmask, Ob);
  gemm(Ob, woT, nullptr, x, 0, X1, 0, 8192, 1024, 1024);

  // temporal attention block
  ln_rows<<<dim3(8192), dim3(256), 0, stream>>>(X1, ta_ng, ta_nb, XN);
  gemm(XN, wqkvT, ta_bqkv, nullptr, 0, QKVb, 1, 8192, 1536, 1024);
  temporal_attn<<<dim3(kB * kL * kHT), dim3(64), 0, stream>>>(QKVb, rope, amask, OTb);
  gemm(OTb, tawoT, nullptr, X1, 0, X1, 0, 8192, 1024, 512);

  // feed-forward block
  ln_rows<<<dim3(8192), dim3(256), 0, stream>>>(X1, ff_ng, ff_nb, XN);
  gemm(XN, ffw1T, nullptr, nullptr, 1, Hb, 1, 8192, 4096, 1024);
  gemm(Hb, ffw2T, nullptr, X1, 0, d_out, 0, 8192, 1024, 4096);
}